// Round 1
// baseline (2325.951 us; speedup 1.0000x reference)
//
#include <hip/hip_runtime.h>
#include <stdint.h>

#define TPB 256

// Problem constants
constexpr int BN   = 64;          // batch
constexpr int CCH  = 3;           // channels
constexpr int HWS  = 262144;      // H*W = 512*512
constexpr int LOG_HW = 18;
constexpr int NPS  = 786432;      // C*H*W per sample
constexpr int KSEL = 196608;      // K_UPPER
constexpr int KCAP = 200704;      // KSEL + 4096 slack for duplicate boundary keys
constexpr int NB_T = 32;          // blocks/sample for full-N passes
constexpr int CH_T = NPS / NB_T;  // 24576
constexpr int NB_S = 16;          // blocks/sample for sort passes
constexpr int CH_S = KCAP / NB_S; // 12544 (49 tiles of 256)
constexpr int NBINS = 2048;

// ws layout (u32 offsets)
constexpr int WS_MN   = 0;        // f32[192]
constexpr int WS_MX   = 192;      // f32[192]
constexpr int WS_V1   = 384;
constexpr int WS_B1   = 448;
constexpr int WS_V12  = 512;
constexpr int WS_B2   = 576;
constexpr int WS_GS   = 640;      // exact K-th key G*
constexpr int WS_KP   = 704;      // compacted count per sample
constexpr int WS_CNT  = 768;      // u32[64*32]
constexpr int WS_COFF = 2816;     // u32[64*32]
constexpr int WS_THA  = 8192;
constexpr int WS_THB  = WS_THA + BN * NBINS;
constexpr int WS_THC  = WS_THB + BN * NBINS;
constexpr int WS_H    = WS_THC + BN * NBINS;                    // u32[64][2048][16]
constexpr size_t WS_IDX0 = (size_t)WS_H + (size_t)BN * NBINS * NB_S;
constexpr size_t WS_IDX1 = WS_IDX0 + (size_t)BN * KCAP;
constexpr size_t WS_NEEDED_BYTES = (WS_IDX1 + (size_t)BN * KCAP) * 4;

// ---------------- threefry2x32 (JAX-exact) ----------------
__device__ __forceinline__ unsigned rotl32(unsigned x, int r) { return (x << r) | (x >> (32 - r)); }

__device__ __forceinline__ void tf4(unsigned& x0, unsigned& x1, int a, int b, int c, int d) {
  x0 += x1; x1 = rotl32(x1, a); x1 ^= x0;
  x0 += x1; x1 = rotl32(x1, b); x1 ^= x0;
  x0 += x1; x1 = rotl32(x1, c); x1 ^= x0;
  x0 += x1; x1 = rotl32(x1, d); x1 ^= x0;
}

__device__ __forceinline__ void threefry2x32(unsigned k0, unsigned k1, unsigned c0, unsigned c1,
                                             unsigned& o0, unsigned& o1) {
  const unsigned ks2 = k0 ^ k1 ^ 0x1BD11BDAu;
  unsigned x0 = c0 + k0, x1 = c1 + k1;
  tf4(x0, x1, 13, 15, 26, 6);  x0 += k1;  x1 += ks2 + 1u;
  tf4(x0, x1, 17, 29, 16, 24); x0 += ks2; x1 += k0 + 2u;
  tf4(x0, x1, 13, 15, 26, 6);  x0 += k0;  x1 += k1 + 3u;
  tf4(x0, x1, 17, 29, 16, 24); x0 += k1;  x1 += ks2 + 4u;
  tf4(x0, x1, 13, 15, 26, 6);  x0 += ks2; x1 += k0 + 5u;
  o0 = x0; o1 = x1;
}

// Flip to 0 if the env's JAX predates jax_threefry_partitionable=True default.
#define JAX_THREEFRY_PARTITIONABLE 1

// ---------------- kernels ----------------
__global__ __launch_bounds__(TPB) void k_zero(unsigned* __restrict__ p, int n) {
  int i = blockIdx.x * TPB + threadIdx.x;
  if (i < n) p[i] = 0u;
}

__global__ __launch_bounds__(TPB) void k_mnmx(const float* __restrict__ x,
                                              float* __restrict__ mn, float* __restrict__ mx) {
  __shared__ float smn[TPB], smx[TPB];
  const int bc = blockIdx.x, tid = threadIdx.x;
  const float* base = x + (size_t)bc * HWS;
  float lo = 3.4e38f, hi = -3.4e38f;
  const float4* b4 = (const float4*)base;
  for (int i = tid; i < HWS / 4 - 1; i += TPB) {   // covers [0, HWS-4)
    float4 v = b4[i];
    lo = fminf(lo, fminf(fminf(v.x, v.y), fminf(v.z, v.w)));
    hi = fmaxf(hi, fmaxf(fmaxf(v.x, v.y), fmaxf(v.z, v.w)));
  }
  if (tid < 3) {                                    // elements HWS-4..HWS-2 (exclude last, HWS-1)
    float v = base[HWS - 4 + tid];
    lo = fminf(lo, v); hi = fmaxf(hi, v);
  }
  smn[tid] = lo; smx[tid] = hi; __syncthreads();
  for (int s = TPB / 2; s > 0; s >>= 1) {
    if (tid < s) { smn[tid] = fminf(smn[tid], smn[tid + s]); smx[tid] = fmaxf(smx[tid], smx[tid + s]); }
    __syncthreads();
  }
  if (tid == 0) { mn[bc] = smn[0]; mx[bc] = smx[0]; }
}

__global__ __launch_bounds__(TPB) void k_thrA(const unsigned* __restrict__ gb, unsigned* __restrict__ hist) {
  __shared__ unsigned h[NBINS];
  const int b = blockIdx.y, blk = blockIdx.x, tid = threadIdx.x;
  for (int v = tid; v < NBINS; v += TPB) h[v] = 0u;
  __syncthreads();
  const uint4* g4 = (const uint4*)(gb + (size_t)b * NPS + (size_t)blk * CH_T);
  for (int i = tid; i < CH_T / 4; i += TPB) {
    uint4 v = g4[i];
    atomicAdd(&h[(v.x & 0x7FFFFFFFu) >> 21], 1u);
    atomicAdd(&h[(v.y & 0x7FFFFFFFu) >> 21], 1u);
    atomicAdd(&h[(v.z & 0x7FFFFFFFu) >> 21], 1u);
    atomicAdd(&h[(v.w & 0x7FFFFFFFu) >> 21], 1u);
  }
  __syncthreads();
  unsigned* gh = hist + (size_t)b * NBINS;
  for (int v = tid; v < NBINS; v += TPB) if (h[v]) atomicAdd(&gh[v], h[v]);
}

__global__ __launch_bounds__(TPB) void k_thrBC(const unsigned* __restrict__ gb,
                                               unsigned* __restrict__ hist,
                                               const unsigned* __restrict__ ws, int mode) {
  __shared__ unsigned h[NBINS];
  const int b = blockIdx.y, blk = blockIdx.x, tid = threadIdx.x;
  for (int v = tid; v < NBINS; v += TPB) h[v] = 0u;
  __syncthreads();
  const unsigned sel = (mode == 1) ? ws[WS_V1 + b] : ws[WS_V12 + b];
  const uint4* g4 = (const uint4*)(gb + (size_t)b * NPS + (size_t)blk * CH_T);
  for (int i = tid; i < CH_T / 4; i += TPB) {
    uint4 v = g4[i];
    unsigned a0 = v.x & 0x7FFFFFFFu, a1 = v.y & 0x7FFFFFFFu;
    unsigned a2 = v.z & 0x7FFFFFFFu, a3 = v.w & 0x7FFFFFFFu;
    if (mode == 1) {
      if ((a0 >> 21) == sel) atomicAdd(&h[(a0 >> 10) & 2047u], 1u);
      if ((a1 >> 21) == sel) atomicAdd(&h[(a1 >> 10) & 2047u], 1u);
      if ((a2 >> 21) == sel) atomicAdd(&h[(a2 >> 10) & 2047u], 1u);
      if ((a3 >> 21) == sel) atomicAdd(&h[(a3 >> 10) & 2047u], 1u);
    } else {
      if ((a0 >> 10) == sel) atomicAdd(&h[a0 & 1023u], 1u);
      if ((a1 >> 10) == sel) atomicAdd(&h[a1 & 1023u], 1u);
      if ((a2 >> 10) == sel) atomicAdd(&h[a2 & 1023u], 1u);
      if ((a3 >> 10) == sel) atomicAdd(&h[a3 & 1023u], 1u);
    }
  }
  __syncthreads();
  unsigned* gh = hist + (size_t)b * NBINS;
  for (int v = tid; v < NBINS; v += TPB) if (h[v]) atomicAdd(&gh[v], h[v]);
}

// mode 0: top 11 bits -> v1, base1 ; mode 1: mid 11 bits -> v12, base2 ; mode 2: low 10 bits -> G*, Kp
__global__ __launch_bounds__(TPB) void k_find(const unsigned* __restrict__ hist,
                                              unsigned* __restrict__ ws, int mode) {
  __shared__ unsigned part[TPB];
  const int b = blockIdx.x, tid = threadIdx.x;
  const unsigned* h = hist + (size_t)b * NBINS;
  const int nb = (mode == 2) ? 1024 : 2048;
  const int per = nb / TPB;
  unsigned Kt;
  if (mode == 0)      Kt = (unsigned)KSEL;
  else if (mode == 1) Kt = (unsigned)KSEL - ws[WS_B1 + b];
  else                Kt = (unsigned)KSEL - ws[WS_B2 + b];
  unsigned vals[8];
  unsigned s = 0;
  for (int j = 0; j < per; ++j) { vals[j] = h[tid * per + j]; s += vals[j]; }
  part[tid] = s; __syncthreads();
  for (int off = 1; off < TPB; off <<= 1) {
    unsigned t = (tid >= off) ? part[tid - off] : 0u;
    __syncthreads(); part[tid] += t; __syncthreads();
  }
  unsigned run = part[tid] - s;
  for (int j = 0; j < per; ++j) {
    const unsigned lo = run, c = vals[j];
    run += c;
    if (lo < Kt && Kt <= run) {          // unique bin containing the K-th element
      const unsigned v = (unsigned)(tid * per + j);
      if (mode == 0)      { ws[WS_V1 + b] = v; ws[WS_B1 + b] = lo; }
      else if (mode == 1) { ws[WS_V12 + b] = (ws[WS_V1 + b] << 11) | v; ws[WS_B2 + b] = ws[WS_B1 + b] + lo; }
      else {
        ws[WS_GS + b] = (ws[WS_V12 + b] << 10) | v;
        unsigned kp = ws[WS_B2 + b] + lo + c;      // countLess + dupEq
        if (kp > (unsigned)KCAP) kp = (unsigned)KCAP;
        ws[WS_KP + b] = kp;
      }
    }
  }
}

__global__ __launch_bounds__(TPB) void k_ccount(const unsigned* __restrict__ gb, unsigned* __restrict__ ws) {
  __shared__ unsigned r[TPB];
  const int b = blockIdx.y, blk = blockIdx.x, tid = threadIdx.x;
  const unsigned G = ws[WS_GS + b];
  const uint4* g4 = (const uint4*)(gb + (size_t)b * NPS + (size_t)blk * CH_T);
  unsigned c = 0;
  for (int i = tid; i < CH_T / 4; i += TPB) {
    uint4 v = g4[i];
    c += (unsigned)((v.x & 0x7FFFFFFFu) <= G) + (unsigned)((v.y & 0x7FFFFFFFu) <= G)
       + (unsigned)((v.z & 0x7FFFFFFFu) <= G) + (unsigned)((v.w & 0x7FFFFFFFu) <= G);
  }
  r[tid] = c; __syncthreads();
  for (int s = TPB / 2; s > 0; s >>= 1) { if (tid < s) r[tid] += r[tid + s]; __syncthreads(); }
  if (tid == 0) ws[WS_CNT + b * NB_T + blk] = r[0];
}

__global__ void k_cscan(unsigned* __restrict__ ws) {
  const int b = blockIdx.x;
  if (threadIdx.x == 0) {
    unsigned run = 0;
    for (int j = 0; j < NB_T; ++j) {
      unsigned t = ws[WS_CNT + b * NB_T + j];
      ws[WS_COFF + b * NB_T + j] = run;
      run += t;
    }
  }
}

// index-ordered (stable) compaction of {i : g_bits[i] <= G*}
__global__ __launch_bounds__(TPB) void k_cscatter(const unsigned* __restrict__ gb,
                                                  const unsigned* __restrict__ ws,
                                                  unsigned* __restrict__ idx0) {
  __shared__ unsigned runsel;
  const int b = blockIdx.y, blk = blockIdx.x, tid = threadIdx.x;
  const int lane = tid & 63, wv = tid >> 6;
  const unsigned G = ws[WS_GS + b];
  if (tid == 0) runsel = ws[WS_COFF + b * NB_T + blk];
  __syncthreads();
  const unsigned* g = gb + (size_t)b * NPS;
  unsigned* od = idx0 + (size_t)b * KCAP;
  const unsigned c0 = (unsigned)blk * CH_T;
  for (int t = 0; t < CH_T / TPB; ++t) {
    const unsigned i = c0 + (unsigned)t * TPB + tid;
    const bool sel = ((g[i] & 0x7FFFFFFFu) <= G);
    unsigned long long m = __ballot(sel);
    const unsigned before = (unsigned)__popcll(m & ((1ull << lane) - 1ull));
    const int leader = __ffsll((unsigned long long)m) - 1;
    for (int w = 0; w < 4; ++w) {        // sequential waves => memory order
      __syncthreads();
      if (wv == w && sel) {
        unsigned old = 0;
        if (lane == leader) old = atomicAdd(&runsel, (unsigned)__popcll(m));
        old = __shfl(old, leader, 64);
        const unsigned pos = old + before;
        if (pos < (unsigned)KCAP) od[pos] = i;
      }
    }
  }
}

__global__ __launch_bounds__(TPB) void k_shist(const unsigned* __restrict__ gb,
                                               const unsigned* __restrict__ idxCur,
                                               unsigned* __restrict__ H,
                                               const unsigned* __restrict__ ws, int shift, int nbins) {
  __shared__ unsigned h[NBINS];
  const int b = blockIdx.y, blk = blockIdx.x, tid = threadIdx.x;
  for (int v = tid; v < nbins; v += TPB) h[v] = 0u;
  __syncthreads();
  const unsigned kp = min(ws[WS_KP + b], (unsigned)KCAP);
  const unsigned s0 = (unsigned)blk * CH_S;
  const unsigned s1 = min(s0 + (unsigned)CH_S, kp);
  const unsigned* ic = idxCur + (size_t)b * KCAP;
  const unsigned* g = gb + (size_t)b * NPS;
  for (unsigned i = s0 + tid; i < s1; i += TPB) {
    const unsigned idx = ic[i];
    atomicAdd(&h[((g[idx] & 0x7FFFFFFFu) >> shift) & (unsigned)(nbins - 1)], 1u);
  }
  __syncthreads();
  unsigned* Hb = H + (size_t)b * NBINS * NB_S;
  for (int v = tid; v < nbins; v += TPB) Hb[(size_t)v * NB_S + blk] = h[v];
}

__global__ __launch_bounds__(TPB) void k_sscan(unsigned* __restrict__ H, int nbins) {
  __shared__ unsigned binbase[NBINS];
  __shared__ unsigned part[TPB];
  const int b = blockIdx.x, tid = threadIdx.x;
  unsigned* Hb = H + (size_t)b * NBINS * NB_S;
  const int per = nbins / TPB;
  unsigned tot = 0;
  for (int j = 0; j < per; ++j) {
    const int v = tid * per + j;
    unsigned run = 0;
    unsigned* row = Hb + (size_t)v * NB_S;
    for (int k = 0; k < NB_S; ++k) { unsigned t = row[k]; row[k] = run; run += t; }
    binbase[v] = run;
    tot += run;
  }
  part[tid] = tot; __syncthreads();
  for (int off = 1; off < TPB; off <<= 1) {
    unsigned t = (tid >= off) ? part[tid - off] : 0u;
    __syncthreads(); part[tid] += t; __syncthreads();
  }
  unsigned run2 = part[tid] - tot;
  for (int j = 0; j < per; ++j) {
    const int v = tid * per + j;
    const unsigned c = binbase[v];
    unsigned* row = Hb + (size_t)v * NB_S;
    for (int k = 0; k < NB_S; ++k) row[k] += run2;
    run2 += c;
  }
}

// stable scatter pass (ballot rank within wave, sequential wave phases, LDS running counters)
__global__ __launch_bounds__(TPB) void k_sscatter(const unsigned* __restrict__ gb,
                                                  const unsigned* __restrict__ idxCur,
                                                  unsigned* __restrict__ idxNext,
                                                  const unsigned* __restrict__ H,
                                                  const unsigned* __restrict__ ws, int shift, int nbins) {
  __shared__ unsigned baseLds[NBINS];
  __shared__ unsigned runCnt[NBINS];
  const int b = blockIdx.y, blk = blockIdx.x, tid = threadIdx.x;
  const int lane = tid & 63, wv = tid >> 6;
  const unsigned* Hb = H + (size_t)b * NBINS * NB_S;
  for (int v = tid; v < nbins; v += TPB) { baseLds[v] = Hb[(size_t)v * NB_S + blk]; runCnt[v] = 0u; }
  __syncthreads();
  const unsigned kp = min(ws[WS_KP + b], (unsigned)KCAP);
  const unsigned s0 = (unsigned)blk * CH_S;
  const unsigned s1 = min(s0 + (unsigned)CH_S, kp);
  const unsigned* ic = idxCur + (size_t)b * KCAP;
  unsigned* on = idxNext + (size_t)b * KCAP;
  const unsigned* g = gb + (size_t)b * NPS;
  for (unsigned start = s0; start < s1; start += TPB) {
    const unsigned i = start + tid;
    const bool valid = (i < s1);
    unsigned idx = 0, dig = 0;
    if (valid) { idx = ic[i]; dig = ((g[idx] & 0x7FFFFFFFu) >> shift) & (unsigned)(nbins - 1); }
    unsigned long long vm = __ballot(valid);
    unsigned long long peers = vm;
#pragma unroll
    for (int bit = 0; bit < 11; ++bit) {
      unsigned long long bb = __ballot(valid && ((dig >> bit) & 1u));
      peers &= ((dig >> bit) & 1u) ? bb : ~bb;
    }
    const unsigned before = (unsigned)__popcll(peers & ((1ull << lane) - 1ull));
    const int leader = __ffsll((unsigned long long)peers) - 1;
    unsigned myoff = 0;
    for (int w = 0; w < 4; ++w) {
      __syncthreads();
      if (wv == w && valid) {
        unsigned old = 0;
        if (lane == leader) old = atomicAdd(&runCnt[dig], (unsigned)__popcll(peers));
        old = __shfl(old, leader, 64);
        myoff = old + before;
      }
    }
    if (valid) on[baseLds[dig] + myoff] = idx;
  }
}

__global__ __launch_bounds__(TPB) void k_copy(const float4* __restrict__ x, float4* __restrict__ o) {
  const size_t i = (size_t)blockIdx.x * TPB + threadIdx.x;
  o[i] = x[i];
}

__global__ __launch_bounds__(TPB) void k_fill(const unsigned* __restrict__ idxF,
                                              const unsigned* __restrict__ ws,
                                              float* __restrict__ out) {
  const int b = blockIdx.y;
  const unsigned k = blockIdx.x * TPB + threadIdx.x;   // grid.x = KSEL/TPB exactly
  const unsigned idx = idxF[(size_t)b * KCAP + k];
  const unsigned p = (unsigned)b * (unsigned)KSEL + k; // linear index into (64, K) uniform array
  unsigned bits;
#if JAX_THREEFRY_PARTITIONABLE
  unsigned o0, o1;
  threefry2x32(0u, 42u, 0u, p, o0, o1);
  bits = o0 ^ o1;
#else
  const unsigned TOTU = (unsigned)BN * (unsigned)KSEL;
  const unsigned half = TOTU / 2u;
  unsigned o0, o1;
  if (p < half) { threefry2x32(0u, 42u, p, p + half, o0, o1); bits = o0; }
  else          { threefry2x32(0u, 42u, p - half, p, o0, o1); bits = o1; }
#endif
  const float u = __uint_as_float((bits >> 9) | 0x3f800000u) - 1.0f;
  const unsigned ch = idx >> LOG_HW;
  const float* mnf = (const float*)(ws + WS_MN);
  const float* mxf = (const float*)(ws + WS_MX);
  const float lo = mnf[b * CCH + ch];
  const float hi = mxf[b * CCH + ch];
  out[(size_t)b * NPS + idx] = lo + u * (hi - lo);
}

extern "C" void kernel_launch(void* const* d_in, const int* in_sizes, int n_in,
                              void* d_out, int out_size, void* d_ws, size_t ws_size,
                              hipStream_t stream) {
  const float* x = (const float*)d_in[0];
  const unsigned* gb = (const unsigned*)d_in[1];   // grad bits
  float* out = (float*)d_out;
  unsigned* ws = (unsigned*)d_ws;
  if (ws_size < WS_NEEDED_BYTES) return;           // loud failure instead of OOB

  dim3 blk(TPB);

  // 0. zero the accumulated threshold histograms (re-zeroed every launch/replay)
  k_zero<<<dim3((3 * BN * NBINS + TPB - 1) / TPB), blk, 0, stream>>>(ws + WS_THA, 3 * BN * NBINS);

  // 1. per-channel min/max over first hw-1 elements
  k_mnmx<<<dim3(BN * CCH), blk, 0, stream>>>(x, (float*)(ws + WS_MN), (float*)(ws + WS_MX));

  // 2. exact K-th key G* via 11/11/10-bit histogram refinement
  k_thrA<<<dim3(NB_T, BN), blk, 0, stream>>>(gb, ws + WS_THA);
  k_find<<<dim3(BN), blk, 0, stream>>>(ws + WS_THA, ws, 0);
  k_thrBC<<<dim3(NB_T, BN), blk, 0, stream>>>(gb, ws + WS_THB, ws, 1);
  k_find<<<dim3(BN), blk, 0, stream>>>(ws + WS_THB, ws, 1);
  k_thrBC<<<dim3(NB_T, BN), blk, 0, stream>>>(gb, ws + WS_THC, ws, 2);
  k_find<<<dim3(BN), blk, 0, stream>>>(ws + WS_THC, ws, 2);

  // 3. index-ordered compaction of elements with key <= G*
  k_ccount<<<dim3(NB_T, BN), blk, 0, stream>>>(gb, ws);
  k_cscan<<<dim3(BN), dim3(64), 0, stream>>>(ws);
  k_cscatter<<<dim3(NB_T, BN), blk, 0, stream>>>(gb, ws, ws + WS_IDX0);

  // 4. stable LSD radix sort of compacted entries by g_bits (idx payload, keys re-gathered)
  unsigned* H = ws + WS_H;
  k_shist  <<<dim3(NB_S, BN), blk, 0, stream>>>(gb, ws + WS_IDX0, H, ws, 0, 2048);
  k_sscan  <<<dim3(BN), blk, 0, stream>>>(H, 2048);
  k_sscatter<<<dim3(NB_S, BN), blk, 0, stream>>>(gb, ws + WS_IDX0, ws + WS_IDX1, H, ws, 0, 2048);

  k_shist  <<<dim3(NB_S, BN), blk, 0, stream>>>(gb, ws + WS_IDX1, H, ws, 11, 2048);
  k_sscan  <<<dim3(BN), blk, 0, stream>>>(H, 2048);
  k_sscatter<<<dim3(NB_S, BN), blk, 0, stream>>>(gb, ws + WS_IDX1, ws + WS_IDX0, H, ws, 11, 2048);

  k_shist  <<<dim3(NB_S, BN), blk, 0, stream>>>(gb, ws + WS_IDX0, H, ws, 22, 1024);
  k_sscan  <<<dim3(BN), blk, 0, stream>>>(H, 1024);
  k_sscatter<<<dim3(NB_S, BN), blk, 0, stream>>>(gb, ws + WS_IDX0, ws + WS_IDX1, H, ws, 22, 1024);

  // 5. out = x, then scatter fills at the K lowest-|grad| positions in top_k order
  k_copy<<<dim3((int)(((size_t)BN * NPS / 4) / TPB)), blk, 0, stream>>>((const float4*)x, (float4*)out);
  k_fill<<<dim3(KSEL / TPB, BN), blk, 0, stream>>>(ws + WS_IDX1, ws, out);
}

// Round 2
// 1312.401 us; speedup vs baseline: 1.7723x; 1.7723x over previous
//
#include <hip/hip_runtime.h>
#include <stdint.h>

#define TPB 256

// Problem constants
constexpr int BN   = 64;          // batch
constexpr int CCH  = 3;           // channels
constexpr int HWS  = 262144;      // H*W = 512*512
constexpr int LOG_HW = 18;
constexpr int NPS  = 786432;      // C*H*W per sample
constexpr int KSEL = 196608;      // K_UPPER
constexpr int KCAP = 200704;      // KSEL + 4096 slack for duplicate boundary keys
constexpr int NB_T = 32;          // blocks/sample for full-N passes
constexpr int CH_T = NPS / NB_T;  // 24576
constexpr int NB_S = 8;           // blocks/sample for sort passes
constexpr int CH_S = KCAP / NB_S; // 25088
constexpr int NBINS = 2048;

// ws layout (u32 offsets)
constexpr int WS_MN   = 0;        // f32[192]
constexpr int WS_MX   = 192;      // f32[192]
constexpr int WS_V1   = 384;
constexpr int WS_B1   = 448;
constexpr int WS_V12  = 512;
constexpr int WS_B2   = 576;
constexpr int WS_GS   = 640;      // exact K-th key G*
constexpr int WS_KP   = 704;      // compacted count per sample
constexpr int WS_CNT  = 768;      // u32[64*32]
constexpr int WS_COFF = 2816;     // u32[64*32]
constexpr int WS_THA  = 8192;
constexpr int WS_THB  = WS_THA + BN * NBINS;
constexpr int WS_THC  = WS_THB + BN * NBINS;
constexpr int WS_H    = WS_THC + BN * NBINS;                    // u32[64][2048][NB_S]
constexpr size_t WS_FIX_END = (size_t)WS_H + (size_t)BN * NBINS * NB_S;  // 1,449,984 u32
constexpr size_t RECW = (size_t)BN * KCAP * 2;   // u32 words per uint2 record buffer
constexpr size_t IDXW = (size_t)BN * KCAP;       // u32 words per idx-only buffer

// ---------------- threefry2x32 (JAX-exact, partitionable stream) ----------------
__device__ __forceinline__ unsigned rotl32(unsigned x, int r) { return (x << r) | (x >> (32 - r)); }

__device__ __forceinline__ void tf4(unsigned& x0, unsigned& x1, int a, int b, int c, int d) {
  x0 += x1; x1 = rotl32(x1, a); x1 ^= x0;
  x0 += x1; x1 = rotl32(x1, b); x1 ^= x0;
  x0 += x1; x1 = rotl32(x1, c); x1 ^= x0;
  x0 += x1; x1 = rotl32(x1, d); x1 ^= x0;
}

__device__ __forceinline__ void threefry2x32(unsigned k0, unsigned k1, unsigned c0, unsigned c1,
                                             unsigned& o0, unsigned& o1) {
  const unsigned ks2 = k0 ^ k1 ^ 0x1BD11BDAu;
  unsigned x0 = c0 + k0, x1 = c1 + k1;
  tf4(x0, x1, 13, 15, 26, 6);  x0 += k1;  x1 += ks2 + 1u;
  tf4(x0, x1, 17, 29, 16, 24); x0 += ks2; x1 += k0 + 2u;
  tf4(x0, x1, 13, 15, 26, 6);  x0 += k0;  x1 += k1 + 3u;
  tf4(x0, x1, 17, 29, 16, 24); x0 += k1;  x1 += ks2 + 4u;
  tf4(x0, x1, 13, 15, 26, 6);  x0 += ks2; x1 += k0 + 5u;
  o0 = x0; o1 = x1;
}

// ---------------- kernels ----------------
__global__ __launch_bounds__(TPB) void k_zero(unsigned* __restrict__ p, int n) {
  int i = blockIdx.x * TPB + threadIdx.x;
  if (i < n) p[i] = 0u;
}

__global__ __launch_bounds__(TPB) void k_mnmx(const float* __restrict__ x,
                                              float* __restrict__ mn, float* __restrict__ mx) {
  __shared__ float smn[TPB], smx[TPB];
  const int bc = blockIdx.x, tid = threadIdx.x;
  const float* base = x + (size_t)bc * HWS;
  float lo = 3.4e38f, hi = -3.4e38f;
  const float4* b4 = (const float4*)base;
  for (int i = tid; i < HWS / 4 - 1; i += TPB) {   // covers [0, HWS-4)
    float4 v = b4[i];
    lo = fminf(lo, fminf(fminf(v.x, v.y), fminf(v.z, v.w)));
    hi = fmaxf(hi, fmaxf(fmaxf(v.x, v.y), fmaxf(v.z, v.w)));
  }
  if (tid < 3) {                                    // elements HWS-4..HWS-2 (exclude last)
    float v = base[HWS - 4 + tid];
    lo = fminf(lo, v); hi = fmaxf(hi, v);
  }
  smn[tid] = lo; smx[tid] = hi; __syncthreads();
  for (int s = TPB / 2; s > 0; s >>= 1) {
    if (tid < s) { smn[tid] = fminf(smn[tid], smn[tid + s]); smx[tid] = fmaxf(smx[tid], smx[tid + s]); }
    __syncthreads();
  }
  if (tid == 0) { mn[bc] = smn[0]; mx[bc] = smx[0]; }
}

__global__ __launch_bounds__(TPB) void k_thrA(const unsigned* __restrict__ gb, unsigned* __restrict__ hist) {
  __shared__ unsigned h[NBINS];
  const int b = blockIdx.y, blk = blockIdx.x, tid = threadIdx.x;
  for (int v = tid; v < NBINS; v += TPB) h[v] = 0u;
  __syncthreads();
  const uint4* g4 = (const uint4*)(gb + (size_t)b * NPS + (size_t)blk * CH_T);
  for (int i = tid; i < CH_T / 4; i += TPB) {
    uint4 v = g4[i];
    atomicAdd(&h[(v.x & 0x7FFFFFFFu) >> 21], 1u);
    atomicAdd(&h[(v.y & 0x7FFFFFFFu) >> 21], 1u);
    atomicAdd(&h[(v.z & 0x7FFFFFFFu) >> 21], 1u);
    atomicAdd(&h[(v.w & 0x7FFFFFFFu) >> 21], 1u);
  }
  __syncthreads();
  unsigned* gh = hist + (size_t)b * NBINS;
  for (int v = tid; v < NBINS; v += TPB) if (h[v]) atomicAdd(&gh[v], h[v]);
}

__global__ __launch_bounds__(TPB) void k_thrBC(const unsigned* __restrict__ gb,
                                               unsigned* __restrict__ hist,
                                               const unsigned* __restrict__ ws, int mode) {
  __shared__ unsigned h[NBINS];
  const int b = blockIdx.y, blk = blockIdx.x, tid = threadIdx.x;
  for (int v = tid; v < NBINS; v += TPB) h[v] = 0u;
  __syncthreads();
  const unsigned sel = (mode == 1) ? ws[WS_V1 + b] : ws[WS_V12 + b];
  const uint4* g4 = (const uint4*)(gb + (size_t)b * NPS + (size_t)blk * CH_T);
  for (int i = tid; i < CH_T / 4; i += TPB) {
    uint4 v = g4[i];
    unsigned a0 = v.x & 0x7FFFFFFFu, a1 = v.y & 0x7FFFFFFFu;
    unsigned a2 = v.z & 0x7FFFFFFFu, a3 = v.w & 0x7FFFFFFFu;
    if (mode == 1) {
      if ((a0 >> 21) == sel) atomicAdd(&h[(a0 >> 10) & 2047u], 1u);
      if ((a1 >> 21) == sel) atomicAdd(&h[(a1 >> 10) & 2047u], 1u);
      if ((a2 >> 21) == sel) atomicAdd(&h[(a2 >> 10) & 2047u], 1u);
      if ((a3 >> 21) == sel) atomicAdd(&h[(a3 >> 10) & 2047u], 1u);
    } else {
      if ((a0 >> 10) == sel) atomicAdd(&h[a0 & 1023u], 1u);
      if ((a1 >> 10) == sel) atomicAdd(&h[a1 & 1023u], 1u);
      if ((a2 >> 10) == sel) atomicAdd(&h[a2 & 1023u], 1u);
      if ((a3 >> 10) == sel) atomicAdd(&h[a3 & 1023u], 1u);
    }
  }
  __syncthreads();
  unsigned* gh = hist + (size_t)b * NBINS;
  for (int v = tid; v < NBINS; v += TPB) if (h[v]) atomicAdd(&gh[v], h[v]);
}

// mode 0: top 11 bits -> v1, base1 ; mode 1: mid 11 bits -> v12, base2 ; mode 2: low 10 bits -> G*, Kp
__global__ __launch_bounds__(TPB) void k_find(const unsigned* __restrict__ hist,
                                              unsigned* __restrict__ ws, int mode) {
  __shared__ unsigned part[TPB];
  const int b = blockIdx.x, tid = threadIdx.x;
  const unsigned* h = hist + (size_t)b * NBINS;
  const int nb = (mode == 2) ? 1024 : 2048;
  const int per = nb / TPB;
  unsigned Kt;
  if (mode == 0)      Kt = (unsigned)KSEL;
  else if (mode == 1) Kt = (unsigned)KSEL - ws[WS_B1 + b];
  else                Kt = (unsigned)KSEL - ws[WS_B2 + b];
  unsigned vals[8];
  unsigned s = 0;
  for (int j = 0; j < per; ++j) { vals[j] = h[tid * per + j]; s += vals[j]; }
  part[tid] = s; __syncthreads();
  for (int off = 1; off < TPB; off <<= 1) {
    unsigned t = (tid >= off) ? part[tid - off] : 0u;
    __syncthreads(); part[tid] += t; __syncthreads();
  }
  unsigned run = part[tid] - s;
  for (int j = 0; j < per; ++j) {
    const unsigned lo = run, c = vals[j];
    run += c;
    if (lo < Kt && Kt <= run) {          // unique bin containing the K-th element
      const unsigned v = (unsigned)(tid * per + j);
      if (mode == 0)      { ws[WS_V1 + b] = v; ws[WS_B1 + b] = lo; }
      else if (mode == 1) { ws[WS_V12 + b] = (ws[WS_V1 + b] << 11) | v; ws[WS_B2 + b] = ws[WS_B1 + b] + lo; }
      else {
        ws[WS_GS + b] = (ws[WS_V12 + b] << 10) | v;
        unsigned kp = ws[WS_B2 + b] + lo + c;      // countLess + dupEq
        if (kp > (unsigned)KCAP) kp = (unsigned)KCAP;
        ws[WS_KP + b] = kp;
      }
    }
  }
}

__global__ __launch_bounds__(TPB) void k_ccount(const unsigned* __restrict__ gb, unsigned* __restrict__ ws) {
  __shared__ unsigned r[TPB];
  const int b = blockIdx.y, blk = blockIdx.x, tid = threadIdx.x;
  const unsigned G = ws[WS_GS + b];
  const uint4* g4 = (const uint4*)(gb + (size_t)b * NPS + (size_t)blk * CH_T);
  unsigned c = 0;
  for (int i = tid; i < CH_T / 4; i += TPB) {
    uint4 v = g4[i];
    c += (unsigned)((v.x & 0x7FFFFFFFu) <= G) + (unsigned)((v.y & 0x7FFFFFFFu) <= G)
       + (unsigned)((v.z & 0x7FFFFFFFu) <= G) + (unsigned)((v.w & 0x7FFFFFFFu) <= G);
  }
  r[tid] = c; __syncthreads();
  for (int s = TPB / 2; s > 0; s >>= 1) { if (tid < s) r[tid] += r[tid + s]; __syncthreads(); }
  if (tid == 0) ws[WS_CNT + b * NB_T + blk] = r[0];
}

__global__ void k_cscan(unsigned* __restrict__ ws) {
  const int b = blockIdx.x;
  if (threadIdx.x == 0) {
    unsigned run = 0;
    for (int j = 0; j < NB_T; ++j) {
      unsigned t = ws[WS_CNT + b * NB_T + j];
      ws[WS_COFF + b * NB_T + j] = run;
      run += t;
    }
  }
}

// index-ordered (stable) compaction of {i : key[i] <= G*}; parallel waves, 2 barriers/1024
template<int OUTREC>
__global__ __launch_bounds__(TPB) void k_cscatter(const unsigned* __restrict__ gb,
                                                  const unsigned* __restrict__ ws,
                                                  void* __restrict__ outB) {
  __shared__ unsigned waveTot[4];
  __shared__ unsigned runBase;
  const int b = blockIdx.y, blk = blockIdx.x, tid = threadIdx.x;
  const int lane = tid & 63, wv = tid >> 6;
  const unsigned long long ltm = (1ull << lane) - 1ull;
  const unsigned G = ws[WS_GS + b];
  if (tid == 0) runBase = ws[WS_COFF + b * NB_T + blk];
  __syncthreads();
  const unsigned* g = gb + (size_t)b * NPS;
  uint2*    oR = (uint2*)outB    + (size_t)b * KCAP;
  unsigned* oI = (unsigned*)outB + (size_t)b * KCAP;
  const unsigned c0 = (unsigned)blk * CH_T;
  for (int t = 0; t < CH_T / 1024; ++t) {
    const unsigned base = c0 + (unsigned)t * 1024u + (unsigned)wv * 256u;
    unsigned key[4], wloc[4];
    bool sel[4];
    unsigned run = 0;
#pragma unroll
    for (int c = 0; c < 4; ++c) {
      const unsigned i = base + (unsigned)c * 64u + (unsigned)lane;
      key[c] = g[i] & 0x7FFFFFFFu;
      sel[c] = (key[c] <= G);
      unsigned long long m = __ballot(sel[c]);
      wloc[c] = run + (unsigned)__popcll(m & ltm);
      run += (unsigned)__popcll(m);
    }
    if (lane == 0) waveTot[wv] = run;
    __syncthreads();
    unsigned wpre = 0;
    for (int w = 0; w < wv; ++w) wpre += waveTot[w];
    const unsigned rb = runBase;
#pragma unroll
    for (int c = 0; c < 4; ++c) {
      if (sel[c]) {
        const unsigned pos = rb + wpre + wloc[c];
        if (pos < (unsigned)KCAP) {
          const unsigned i = base + (unsigned)c * 64u + (unsigned)lane;
          if (OUTREC) { uint2 r; r.x = i; r.y = key[c]; oR[pos] = r; }
          else        { oI[pos] = i; }
        }
      }
    }
    __syncthreads();
    if (tid == 0) runBase += waveTot[0] + waveTot[1] + waveTot[2] + waveTot[3];
  }
}

template<int INREC>
__global__ __launch_bounds__(TPB) void k_shist(const unsigned* __restrict__ gb,
                                               const void* __restrict__ inB,
                                               unsigned* __restrict__ H,
                                               const unsigned* __restrict__ ws, int shift) {
  __shared__ unsigned h[NBINS];
  const int b = blockIdx.y, blk = blockIdx.x, tid = threadIdx.x;
  for (int v = tid; v < NBINS; v += TPB) h[v] = 0u;
  __syncthreads();
  const unsigned kp = min(ws[WS_KP + b], (unsigned)KCAP);
  const unsigned s0 = (unsigned)blk * CH_S;
  const unsigned s1 = min(s0 + (unsigned)CH_S, kp);
  const uint2*    iR = (const uint2*)inB    + (size_t)b * KCAP;
  const unsigned* iI = (const unsigned*)inB + (size_t)b * KCAP;
  const unsigned* g = gb + (size_t)b * NPS;
  for (unsigned i = s0 + tid; i < s1; i += TPB) {
    unsigned key;
    if (INREC) key = iR[i].y;
    else       key = g[iI[i]] & 0x7FFFFFFFu;
    atomicAdd(&h[(key >> shift) & 2047u], 1u);
  }
  __syncthreads();
  unsigned* Hb = H + (size_t)b * NBINS * NB_S;
  for (int v = tid; v < NBINS; v += TPB) Hb[(size_t)v * NB_S + blk] = h[v];
}

__global__ __launch_bounds__(TPB) void k_sscan(unsigned* __restrict__ H) {
  __shared__ unsigned binbase[NBINS];
  __shared__ unsigned part[TPB];
  const int b = blockIdx.x, tid = threadIdx.x;
  unsigned* Hb = H + (size_t)b * NBINS * NB_S;
  const int per = NBINS / TPB;
  unsigned tot = 0;
  for (int j = 0; j < per; ++j) {
    const int v = tid * per + j;
    unsigned run = 0;
    unsigned* row = Hb + (size_t)v * NB_S;
    for (int k = 0; k < NB_S; ++k) { unsigned t = row[k]; row[k] = run; run += t; }
    binbase[v] = run;
    tot += run;
  }
  part[tid] = tot; __syncthreads();
  for (int off = 1; off < TPB; off <<= 1) {
    unsigned t = (tid >= off) ? part[tid - off] : 0u;
    __syncthreads(); part[tid] += t; __syncthreads();
  }
  unsigned run2 = part[tid] - tot;
  for (int j = 0; j < per; ++j) {
    const int v = tid * per + j;
    const unsigned c = binbase[v];
    unsigned* row = Hb + (size_t)v * NB_S;
    for (int k = 0; k < NB_S; ++k) row[k] += run2;
    run2 += c;
  }
}

// Stable radix-sort scatter pass. Order = (block, tile, wave, chunk, lane) = memory order.
// Parallel waves via per-wave LDS histograms + cross-wave per-digit prefix. 4 barriers/1024.
// OUTMODE: 0 = write u32 idx, 1 = write uint2 record, 2 = final pass: fill out[] directly.
template<int INREC, int OUTMODE>
__global__ __launch_bounds__(TPB) void k_sort(const unsigned* __restrict__ gb,
                                              const void* __restrict__ inB,
                                              void* __restrict__ outB,
                                              const unsigned* __restrict__ H,
                                              const unsigned* __restrict__ ws,
                                              float* __restrict__ outF,
                                              int shift) {
  __shared__ unsigned wh[4][NBINS];    // per-wave per-digit count -> absolute base
  __shared__ unsigned gbase[NBINS];    // running global base for this block's bins
  const int b = blockIdx.y, blk = blockIdx.x, tid = threadIdx.x;
  const int lane = tid & 63, wv = tid >> 6;
  const unsigned long long ltm = (1ull << lane) - 1ull;
  const unsigned* Hb = H + (size_t)b * NBINS * NB_S;
  for (int v = tid; v < NBINS; v += TPB) gbase[v] = Hb[(size_t)v * NB_S + blk];
  const unsigned kp = min(ws[WS_KP + b], (unsigned)KCAP);
  const unsigned s0 = (unsigned)blk * CH_S;
  const unsigned s1 = min(s0 + (unsigned)CH_S, kp);
  const uint2*    iR = (const uint2*)inB    + (size_t)b * KCAP;
  const unsigned* iI = (const unsigned*)inB + (size_t)b * KCAP;
  const unsigned* g  = gb + (size_t)b * NPS;
  uint2*    oR = (uint2*)outB    + (size_t)b * KCAP;
  unsigned* oI = (unsigned*)outB + (size_t)b * KCAP;

  for (unsigned t0 = s0; t0 < s1; t0 += 1024u) {
    // clear wave histograms (vectorized: 4*NBINS words = NBINS uint4)
    uint4* whv = (uint4*)&wh[0][0];
    for (int j = tid; j < NBINS; j += TPB) whv[j] = make_uint4(0u, 0u, 0u, 0u);
    __syncthreads();

    const unsigned base = t0 + (unsigned)wv * 256u;
    unsigned idx[4], key[4], dig[4], wloc[4];
    bool valid[4];
#pragma unroll
    for (int c = 0; c < 4; ++c) {
      const unsigned i = base + (unsigned)c * 64u + (unsigned)lane;
      valid[c] = (i < s1);
      unsigned k = 0; idx[c] = 0;
      if (valid[c]) {
        if (INREC) { uint2 r = iR[i]; idx[c] = r.x; k = r.y; }
        else       { idx[c] = iI[i]; k = g[idx[c]] & 0x7FFFFFFFu; }
      }
      key[c] = k;
      dig[c] = (k >> shift) & 2047u;
      unsigned long long peers = __ballot(valid[c]);
#pragma unroll
      for (int bit = 0; bit < 11; ++bit) {
        unsigned long long bb = __ballot(valid[c] && ((dig[c] >> bit) & 1u));
        peers &= ((dig[c] >> bit) & 1u) ? bb : ~bb;
      }
      const unsigned before = (unsigned)__popcll(peers & ltm);
      int ldr = __ffsll((unsigned long long)peers) - 1;
      if (ldr < 0) ldr = 0;
      unsigned old = 0;
      if (valid[c] && lane == ldr) old = atomicAdd(&wh[wv][dig[c]], (unsigned)__popcll(peers));
      old = __shfl(old, ldr, 64);
      wloc[c] = old + before;
    }
    __syncthreads();

    // per-digit cross-wave exclusive prefix -> absolute bases; advance gbase
    for (int d = tid; d < NBINS; d += TPB) {
      const unsigned w0 = wh[0][d], w1 = wh[1][d], w2 = wh[2][d], w3 = wh[3][d];
      const unsigned o = gbase[d];
      wh[0][d] = o; wh[1][d] = o + w0; wh[2][d] = o + w0 + w1; wh[3][d] = o + w0 + w1 + w2;
      gbase[d] = o + w0 + w1 + w2 + w3;
    }
    __syncthreads();

#pragma unroll
    for (int c = 0; c < 4; ++c) {
      if (valid[c]) {
        const unsigned pos = wh[wv][dig[c]] + wloc[c];
        if (OUTMODE == 0) {
          oI[pos] = idx[c];
        } else if (OUTMODE == 1) {
          uint2 r; r.x = idx[c]; r.y = key[c]; oR[pos] = r;
        } else {
          if (pos < (unsigned)KSEL) {            // pos == exact rank within sample
            const unsigned p = (unsigned)b * (unsigned)KSEL + pos;
            unsigned o0, o1;
            threefry2x32(0u, 42u, 0u, p, o0, o1);
            const unsigned bits = o0 ^ o1;
            const float u = __uint_as_float((bits >> 9) | 0x3f800000u) - 1.0f;
            const unsigned ch = idx[c] >> LOG_HW;
            const float* mnf = (const float*)(ws + WS_MN);
            const float* mxf = (const float*)(ws + WS_MX);
            const float lo = mnf[b * CCH + ch];
            const float hi = mxf[b * CCH + ch];
            outF[(size_t)b * NPS + idx[c]] = lo + u * (hi - lo);
          }
        }
      }
    }
    __syncthreads();   // protect wh/gbase before next tile's clear
  }
}

__global__ __launch_bounds__(TPB) void k_copy(const float4* __restrict__ x, float4* __restrict__ o) {
  const size_t i = (size_t)blockIdx.x * TPB + threadIdx.x;
  o[i] = x[i];
}

extern "C" void kernel_launch(void* const* d_in, const int* in_sizes, int n_in,
                              void* d_out, int out_size, void* d_ws, size_t ws_size,
                              hipStream_t stream) {
  const float* x = (const float*)d_in[0];
  const unsigned* gb = (const unsigned*)d_in[1];   // grad bits
  float* out = (float*)d_out;
  unsigned* ws = (unsigned*)d_ws;

  const bool rec = ws_size >= (WS_FIX_END + 2 * RECW) * 4;          // 211 MB: (idx,key) records
  if (!rec && ws_size < (WS_FIX_END + 2 * IDXW) * 4) return;        // 109 MB known-safe fallback
  void* bufA = (void*)(ws + WS_FIX_END);
  void* bufB = rec ? (void*)(ws + WS_FIX_END + RECW) : (void*)(ws + WS_FIX_END + IDXW);
  unsigned* H = ws + WS_H;

  dim3 blk(TPB);

  // 0. out = x (must precede the final fill pass); zero threshold histograms
  k_copy<<<dim3((int)(((size_t)BN * NPS / 4) / TPB)), blk, 0, stream>>>((const float4*)x, (float4*)out);
  k_zero<<<dim3((3 * BN * NBINS + TPB - 1) / TPB), blk, 0, stream>>>(ws + WS_THA, 3 * BN * NBINS);

  // 1. per-channel min/max over first hw-1 elements
  k_mnmx<<<dim3(BN * CCH), blk, 0, stream>>>(x, (float*)(ws + WS_MN), (float*)(ws + WS_MX));

  // 2. exact K-th key G* via 11/11/10-bit histogram refinement
  k_thrA<<<dim3(NB_T, BN), blk, 0, stream>>>(gb, ws + WS_THA);
  k_find<<<dim3(BN), blk, 0, stream>>>(ws + WS_THA, ws, 0);
  k_thrBC<<<dim3(NB_T, BN), blk, 0, stream>>>(gb, ws + WS_THB, ws, 1);
  k_find<<<dim3(BN), blk, 0, stream>>>(ws + WS_THB, ws, 1);
  k_thrBC<<<dim3(NB_T, BN), blk, 0, stream>>>(gb, ws + WS_THC, ws, 2);
  k_find<<<dim3(BN), blk, 0, stream>>>(ws + WS_THC, ws, 2);

  // 3. index-ordered compaction of elements with key <= G*  (emits (idx,key) records if room)
  k_ccount<<<dim3(NB_T, BN), blk, 0, stream>>>(gb, ws);
  k_cscan<<<dim3(BN), dim3(64), 0, stream>>>(ws);
  if (rec) k_cscatter<1><<<dim3(NB_T, BN), blk, 0, stream>>>(gb, ws, bufA);
  else     k_cscatter<0><<<dim3(NB_T, BN), blk, 0, stream>>>(gb, ws, bufA);

  // 4. stable LSD radix sort (11/11/10) ; final pass writes fills directly (pos == rank)
  if (rec) {
    k_shist<1><<<dim3(NB_S, BN), blk, 0, stream>>>(gb, bufA, H, ws, 0);
    k_sscan <<<dim3(BN), blk, 0, stream>>>(H);
    k_sort<1, 1><<<dim3(NB_S, BN), blk, 0, stream>>>(gb, bufA, bufB, H, ws, out, 0);

    k_shist<1><<<dim3(NB_S, BN), blk, 0, stream>>>(gb, bufB, H, ws, 11);
    k_sscan <<<dim3(BN), blk, 0, stream>>>(H);
    k_sort<1, 1><<<dim3(NB_S, BN), blk, 0, stream>>>(gb, bufB, bufA, H, ws, out, 11);

    k_shist<1><<<dim3(NB_S, BN), blk, 0, stream>>>(gb, bufA, H, ws, 22);
    k_sscan <<<dim3(BN), blk, 0, stream>>>(H);
    k_sort<1, 2><<<dim3(NB_S, BN), blk, 0, stream>>>(gb, bufA, bufB, H, ws, out, 22);
  } else {
    k_shist<0><<<dim3(NB_S, BN), blk, 0, stream>>>(gb, bufA, H, ws, 0);
    k_sscan <<<dim3(BN), blk, 0, stream>>>(H);
    k_sort<0, 0><<<dim3(NB_S, BN), blk, 0, stream>>>(gb, bufA, bufB, H, ws, out, 0);

    k_shist<0><<<dim3(NB_S, BN), blk, 0, stream>>>(gb, bufB, H, ws, 11);
    k_sscan <<<dim3(BN), blk, 0, stream>>>(H);
    k_sort<0, 0><<<dim3(NB_S, BN), blk, 0, stream>>>(gb, bufB, bufA, H, ws, out, 11);

    k_shist<0><<<dim3(NB_S, BN), blk, 0, stream>>>(gb, bufA, H, ws, 22);
    k_sscan <<<dim3(BN), blk, 0, stream>>>(H);
    k_sort<0, 2><<<dim3(NB_S, BN), blk, 0, stream>>>(gb, bufA, bufB, H, ws, out, 22);
  }
}

// Round 3
// 908.091 us; speedup vs baseline: 2.5614x; 1.4452x over previous
//
#include <hip/hip_runtime.h>
#include <stdint.h>

#define TPB 256

// Problem constants
constexpr int BN   = 64;          // batch
constexpr int CCH  = 3;           // channels
constexpr int HWS  = 262144;      // H*W
constexpr int LOG_HW = 18;
constexpr int NPS  = 786432;      // C*H*W per sample
constexpr int KSEL = 196608;      // K_UPPER
constexpr int KCAP = 200704;      // KSEL + slack for boundary duplicates (=16*12544)
constexpr int NB_T = 32;          // blocks/sample for full-N passes
constexpr int CH_T = NPS / NB_T;  // 24576
constexpr int NB_S = 16;          // blocks/sample for sort passes
constexpr int CH_S = KCAP / NB_S; // 12544 = 256*49
constexpr int NBINS = 2048;       // threshold-refinement bins
constexpr int SUB  = 8;           // sub-blocks per (b,c) in copy+mnmx

// ws layout (u32 offsets)
constexpr int WS_MN   = 0;        // f32[192]
constexpr int WS_MX   = 192;      // f32[192]
constexpr int WS_V1   = 384;
constexpr int WS_B1   = 448;
constexpr int WS_V12  = 512;
constexpr int WS_B2   = 576;
constexpr int WS_GS   = 640;      // exact K-th key G*
constexpr int WS_KP   = 704;      // compacted count per sample
constexpr int WS_CNT  = 768;      // u32[64*32]
constexpr int WS_COFF = 2816;     // u32[64*32]
constexpr int WS_MNP  = 4864;     // f32[1536] partial mins
constexpr int WS_MXP  = 6400;     // f32[1536] partial maxs
constexpr int WS_THA  = 8192;
constexpr int WS_THB  = WS_THA + BN * NBINS;
constexpr int WS_THC  = WS_THB + BN * NBINS;
constexpr int WS_H0   = WS_THC + BN * NBINS;        // u32[64][256][16] per pass
constexpr int WS_H1   = WS_H0 + BN * 256 * NB_S;
constexpr int WS_H2   = WS_H1 + BN * 256 * NB_S;
constexpr int WS_H3   = WS_H2 + BN * 256 * NB_S;
constexpr size_t WS_FIX_END = (size_t)WS_H3 + (size_t)BN * 256 * NB_S;  // 1,449,984 words
constexpr size_t RECW = (size_t)BN * KCAP * 2;      // words per uint2 record buffer
constexpr size_t WS_NEEDED_BYTES = (WS_FIX_END + 2 * RECW) * 4;   // 211.3 MB (known-safe)

// ---------------- threefry2x32 (JAX-exact, partitionable stream) ----------------
__device__ __forceinline__ unsigned rotl32(unsigned x, int r) { return (x << r) | (x >> (32 - r)); }

__device__ __forceinline__ void tf4(unsigned& x0, unsigned& x1, int a, int b, int c, int d) {
  x0 += x1; x1 = rotl32(x1, a); x1 ^= x0;
  x0 += x1; x1 = rotl32(x1, b); x1 ^= x0;
  x0 += x1; x1 = rotl32(x1, c); x1 ^= x0;
  x0 += x1; x1 = rotl32(x1, d); x1 ^= x0;
}

__device__ __forceinline__ void threefry2x32(unsigned k0, unsigned k1, unsigned c0, unsigned c1,
                                             unsigned& o0, unsigned& o1) {
  const unsigned ks2 = k0 ^ k1 ^ 0x1BD11BDAu;
  unsigned x0 = c0 + k0, x1 = c1 + k1;
  tf4(x0, x1, 13, 15, 26, 6);  x0 += k1;  x1 += ks2 + 1u;
  tf4(x0, x1, 17, 29, 16, 24); x0 += ks2; x1 += k0 + 2u;
  tf4(x0, x1, 13, 15, 26, 6);  x0 += k0;  x1 += k1 + 3u;
  tf4(x0, x1, 17, 29, 16, 24); x0 += k1;  x1 += ks2 + 4u;
  tf4(x0, x1, 13, 15, 26, 6);  x0 += ks2; x1 += k0 + 5u;
  o0 = x0; o1 = x1;
}

// destblk = pos / 12544 = (pos>>8)/49 ; exact for pos < KCAP (argument <= 783)
__device__ __forceinline__ unsigned divCHS(unsigned pos) {
  return ((pos >> 8) * 1338u) >> 16;
}

// ---------------- kernels ----------------
__global__ __launch_bounds__(TPB) void k_zero(unsigned* __restrict__ p, int n) {
  int i = blockIdx.x * TPB + threadIdx.x;
  if (i < n) p[i] = 0u;
}

// fused out=x copy + per-(b,c) min/max partials (excluding channel's last element)
__global__ __launch_bounds__(TPB) void k_copymn(const float4* __restrict__ x,
                                                float4* __restrict__ o,
                                                unsigned* __restrict__ ws) {
  __shared__ float smn[TPB], smx[TPB];
  const int g = blockIdx.x;            // bc*SUB + sub
  const int bc = g / SUB, sub = g - bc * SUB;
  const int Q4 = HWS / 4 / SUB;        // 8192 float4 per sub-block
  const size_t base4 = (size_t)bc * (HWS / 4) + (size_t)sub * Q4;
  const bool last = (sub == SUB - 1);
  const int tid = threadIdx.x;
  float lo = 3.4e38f, hi = -3.4e38f;
  for (int i = tid; i < Q4; i += TPB) {
    float4 v = x[base4 + i];
    o[base4 + i] = v;
    if (last && i == Q4 - 1) {         // exclude final element of the channel
      lo = fminf(lo, fminf(fminf(v.x, v.y), v.z));
      hi = fmaxf(hi, fmaxf(fmaxf(v.x, v.y), v.z));
    } else {
      lo = fminf(lo, fminf(fminf(v.x, v.y), fminf(v.z, v.w)));
      hi = fmaxf(hi, fmaxf(fmaxf(v.x, v.y), fmaxf(v.z, v.w)));
    }
  }
  smn[tid] = lo; smx[tid] = hi; __syncthreads();
  for (int s = TPB / 2; s > 0; s >>= 1) {
    if (tid < s) { smn[tid] = fminf(smn[tid], smn[tid + s]); smx[tid] = fmaxf(smx[tid], smx[tid + s]); }
    __syncthreads();
  }
  if (tid == 0) {
    ((float*)(ws + WS_MNP))[g] = smn[0];
    ((float*)(ws + WS_MXP))[g] = smx[0];
  }
}

__global__ __launch_bounds__(TPB) void k_mnfin(unsigned* __restrict__ ws) {
  const int t = threadIdx.x;
  if (t < BN * CCH) {
    const float* mnp = (const float*)(ws + WS_MNP);
    const float* mxp = (const float*)(ws + WS_MXP);
    float lo = 3.4e38f, hi = -3.4e38f;
    for (int s = 0; s < SUB; ++s) {
      lo = fminf(lo, mnp[t * SUB + s]);
      hi = fmaxf(hi, mxp[t * SUB + s]);
    }
    ((float*)(ws + WS_MN))[t] = lo;
    ((float*)(ws + WS_MX))[t] = hi;
  }
}

__global__ __launch_bounds__(TPB) void k_thrA(const unsigned* __restrict__ gb, unsigned* __restrict__ hist) {
  __shared__ unsigned h[NBINS];
  const int b = blockIdx.y, blk = blockIdx.x, tid = threadIdx.x;
  for (int v = tid; v < NBINS; v += TPB) h[v] = 0u;
  __syncthreads();
  const uint4* g4 = (const uint4*)(gb + (size_t)b * NPS + (size_t)blk * CH_T);
  for (int i = tid; i < CH_T / 4; i += TPB) {
    uint4 v = g4[i];
    atomicAdd(&h[(v.x & 0x7FFFFFFFu) >> 21], 1u);
    atomicAdd(&h[(v.y & 0x7FFFFFFFu) >> 21], 1u);
    atomicAdd(&h[(v.z & 0x7FFFFFFFu) >> 21], 1u);
    atomicAdd(&h[(v.w & 0x7FFFFFFFu) >> 21], 1u);
  }
  __syncthreads();
  unsigned* gh = hist + (size_t)b * NBINS;
  for (int v = tid; v < NBINS; v += TPB) if (h[v]) atomicAdd(&gh[v], h[v]);
}

__global__ __launch_bounds__(TPB) void k_thrBC(const unsigned* __restrict__ gb,
                                               unsigned* __restrict__ hist,
                                               const unsigned* __restrict__ ws, int mode) {
  __shared__ unsigned h[NBINS];
  const int b = blockIdx.y, blk = blockIdx.x, tid = threadIdx.x;
  for (int v = tid; v < NBINS; v += TPB) h[v] = 0u;
  __syncthreads();
  const unsigned sel = (mode == 1) ? ws[WS_V1 + b] : ws[WS_V12 + b];
  const uint4* g4 = (const uint4*)(gb + (size_t)b * NPS + (size_t)blk * CH_T);
  for (int i = tid; i < CH_T / 4; i += TPB) {
    uint4 v = g4[i];
    unsigned a0 = v.x & 0x7FFFFFFFu, a1 = v.y & 0x7FFFFFFFu;
    unsigned a2 = v.z & 0x7FFFFFFFu, a3 = v.w & 0x7FFFFFFFu;
    if (mode == 1) {
      if ((a0 >> 21) == sel) atomicAdd(&h[(a0 >> 10) & 2047u], 1u);
      if ((a1 >> 21) == sel) atomicAdd(&h[(a1 >> 10) & 2047u], 1u);
      if ((a2 >> 21) == sel) atomicAdd(&h[(a2 >> 10) & 2047u], 1u);
      if ((a3 >> 21) == sel) atomicAdd(&h[(a3 >> 10) & 2047u], 1u);
    } else {
      if ((a0 >> 10) == sel) atomicAdd(&h[a0 & 1023u], 1u);
      if ((a1 >> 10) == sel) atomicAdd(&h[a1 & 1023u], 1u);
      if ((a2 >> 10) == sel) atomicAdd(&h[a2 & 1023u], 1u);
      if ((a3 >> 10) == sel) atomicAdd(&h[a3 & 1023u], 1u);
    }
  }
  __syncthreads();
  unsigned* gh = hist + (size_t)b * NBINS;
  for (int v = tid; v < NBINS; v += TPB) if (h[v]) atomicAdd(&gh[v], h[v]);
}

// mode 0: top 11 bits ; mode 1: mid 11 ; mode 2: low 10 -> G*, Kp
__global__ __launch_bounds__(TPB) void k_find(const unsigned* __restrict__ hist,
                                              unsigned* __restrict__ ws, int mode) {
  __shared__ unsigned part[TPB];
  const int b = blockIdx.x, tid = threadIdx.x;
  const unsigned* h = hist + (size_t)b * NBINS;
  const int nb = (mode == 2) ? 1024 : 2048;
  const int per = nb / TPB;
  unsigned Kt;
  if (mode == 0)      Kt = (unsigned)KSEL;
  else if (mode == 1) Kt = (unsigned)KSEL - ws[WS_B1 + b];
  else                Kt = (unsigned)KSEL - ws[WS_B2 + b];
  unsigned vals[8];
  unsigned s = 0;
  for (int j = 0; j < per; ++j) { vals[j] = h[tid * per + j]; s += vals[j]; }
  part[tid] = s; __syncthreads();
  for (int off = 1; off < TPB; off <<= 1) {
    unsigned t = (tid >= off) ? part[tid - off] : 0u;
    __syncthreads(); part[tid] += t; __syncthreads();
  }
  unsigned run = part[tid] - s;
  for (int j = 0; j < per; ++j) {
    const unsigned lo = run, c = vals[j];
    run += c;
    if (lo < Kt && Kt <= run) {
      const unsigned v = (unsigned)(tid * per + j);
      if (mode == 0)      { ws[WS_V1 + b] = v; ws[WS_B1 + b] = lo; }
      else if (mode == 1) { ws[WS_V12 + b] = (ws[WS_V1 + b] << 11) | v; ws[WS_B2 + b] = ws[WS_B1 + b] + lo; }
      else {
        ws[WS_GS + b] = (ws[WS_V12 + b] << 10) | v;
        unsigned kp = ws[WS_B2 + b] + lo + c;
        if (kp > (unsigned)KCAP) kp = (unsigned)KCAP;
        ws[WS_KP + b] = kp;
      }
    }
  }
}

__global__ __launch_bounds__(TPB) void k_ccount(const unsigned* __restrict__ gb, unsigned* __restrict__ ws) {
  __shared__ unsigned r[TPB];
  const int b = blockIdx.y, blk = blockIdx.x, tid = threadIdx.x;
  const unsigned G = ws[WS_GS + b];
  const uint4* g4 = (const uint4*)(gb + (size_t)b * NPS + (size_t)blk * CH_T);
  unsigned c = 0;
  for (int i = tid; i < CH_T / 4; i += TPB) {
    uint4 v = g4[i];
    c += (unsigned)((v.x & 0x7FFFFFFFu) <= G) + (unsigned)((v.y & 0x7FFFFFFFu) <= G)
       + (unsigned)((v.z & 0x7FFFFFFFu) <= G) + (unsigned)((v.w & 0x7FFFFFFFu) <= G);
  }
  r[tid] = c; __syncthreads();
  for (int s = TPB / 2; s > 0; s >>= 1) { if (tid < s) r[tid] += r[tid + s]; __syncthreads(); }
  if (tid == 0) ws[WS_CNT + b * NB_T + blk] = r[0];
}

__global__ void k_cscan(unsigned* __restrict__ ws) {
  const int b = blockIdx.x;
  if (threadIdx.x == 0) {
    unsigned run = 0;
    for (int j = 0; j < NB_T; ++j) {
      unsigned t = ws[WS_CNT + b * NB_T + j];
      ws[WS_COFF + b * NB_T + j] = run;
      run += t;
    }
  }
}

// index-ordered compaction of {i : key[i] <= G*} -> uint2(idx,key) records,
// fused pass-1 per-destblock digit histogram into H0.
__global__ __launch_bounds__(TPB) void k_cscatter(const unsigned* __restrict__ gb,
                                                  const unsigned* __restrict__ ws,
                                                  uint2* __restrict__ outR,
                                                  unsigned* __restrict__ H0) {
  __shared__ unsigned h2[256 * NB_S];   // 16 KB
  __shared__ unsigned waveTot[4];
  __shared__ unsigned runBase;
  const int b = blockIdx.y, blk = blockIdx.x, tid = threadIdx.x;
  const int lane = tid & 63, wv = tid >> 6;
  const unsigned long long ltm = (1ull << lane) - 1ull;
  const unsigned G = ws[WS_GS + b];
  for (int e = tid; e < 256 * NB_S; e += TPB) h2[e] = 0u;
  if (tid == 0) runBase = ws[WS_COFF + b * NB_T + blk];
  __syncthreads();
  const unsigned* g = gb + (size_t)b * NPS;
  uint2* oR = outR + (size_t)b * KCAP;
  const unsigned c0 = (unsigned)blk * CH_T;
  for (int t = 0; t < CH_T / 1024; ++t) {
    const unsigned base = c0 + (unsigned)t * 1024u + (unsigned)wv * 256u;
    unsigned key[4], wloc[4];
    bool sel[4];
    unsigned run = 0;
#pragma unroll
    for (int c = 0; c < 4; ++c) {
      const unsigned i = base + (unsigned)c * 64u + (unsigned)lane;
      key[c] = g[i] & 0x7FFFFFFFu;
      sel[c] = (key[c] <= G);
      unsigned long long m = __ballot(sel[c]);
      wloc[c] = run + (unsigned)__popcll(m & ltm);
      run += (unsigned)__popcll(m);
    }
    if (lane == 0) waveTot[wv] = run;
    __syncthreads();
    unsigned wpre = 0;
    for (int w = 0; w < wv; ++w) wpre += waveTot[w];
    const unsigned rb = runBase;
#pragma unroll
    for (int c = 0; c < 4; ++c) {
      if (sel[c]) {
        const unsigned pos = rb + wpre + wloc[c];
        if (pos < (unsigned)KCAP) {
          const unsigned i = base + (unsigned)c * 64u + (unsigned)lane;
          uint2 r; r.x = i; r.y = key[c];
          oR[pos] = r;
          atomicAdd(&h2[(key[c] & 255u) * NB_S + divCHS(pos)], 1u);
        }
      }
    }
    __syncthreads();
    if (tid == 0) runBase += waveTot[0] + waveTot[1] + waveTot[2] + waveTot[3];
  }
  __syncthreads();
  unsigned* Hb = H0 + (size_t)b * 256 * NB_S;
  for (int e = tid; e < 256 * NB_S; e += TPB) {
    unsigned c = h2[e];
    if (c) atomicAdd(&Hb[e], c);
  }
}

// per-sample scan of H[b][256][16] counts -> global output bases (lexicographic dig,blk)
__global__ __launch_bounds__(TPB) void k_hscan(unsigned* __restrict__ H) {
  __shared__ unsigned wsum[4];
  const int b = blockIdx.x, tid = threadIdx.x;
  const int lane = tid & 63, wv = tid >> 6;
  unsigned* Hb = H + (size_t)b * 256 * NB_S;
  unsigned row[NB_S];
  unsigned run = 0;
#pragma unroll
  for (int k = 0; k < NB_S; ++k) {
    unsigned t = Hb[tid * NB_S + k];
    row[k] = run; run += t;
  }
  unsigned incl = run;
  for (int off = 1; off < 64; off <<= 1) {
    unsigned t = __shfl_up(incl, off, 64);
    if (lane >= off) incl += t;
  }
  if (lane == 63) wsum[wv] = incl;
  __syncthreads();
  unsigned wpre = 0;
  for (int w = 0; w < wv; ++w) wpre += wsum[w];
  const unsigned excl = incl - run + wpre;
#pragma unroll
  for (int k = 0; k < NB_S; ++k) Hb[tid * NB_S + k] = row[k] + excl;
}

// One stable 8-bit LSD radix pass with LDS-staged coalesced output.
// FINAL=0: write records to outR + accumulate next-pass hist into Hnext.
// FINAL=1: pos == final rank -> threefry fill into outF (no record write).
template<int FINAL>
__global__ __launch_bounds__(TPB) void k_sort8(const uint2* __restrict__ inR,
                                               uint2* __restrict__ outR,
                                               const unsigned* __restrict__ Hcur,
                                               unsigned* __restrict__ Hnext,
                                               const unsigned* __restrict__ ws,
                                               float* __restrict__ outF,
                                               int shift) {
  __shared__ unsigned wh[4][256];        // per-wave digit counts -> per-wave in-tile bases
  __shared__ unsigned gout[256];         // gbase[d] - tstart[d]
  __shared__ unsigned gbase[256];        // running global base per digit
  __shared__ unsigned wsum[4];
  __shared__ uint2    stg[2048];         // staged tile
  __shared__ unsigned h2[256 * NB_S];    // next-pass hist pre-agg
  const int b = blockIdx.y, blk = blockIdx.x, tid = threadIdx.x;
  const int lane = tid & 63, wv = tid >> 6;
  const unsigned long long ltm = (1ull << lane) - 1ull;
  const unsigned kp = min(ws[WS_KP + b], (unsigned)KCAP);
  const unsigned s0 = (unsigned)blk * CH_S;
  const unsigned s1 = min(s0 + (unsigned)CH_S, kp);
  const uint2* in = inR + (size_t)b * KCAP;
  uint2* out = outR + (size_t)b * KCAP;

  for (int d = tid; d < 256; d += TPB) gbase[d] = Hcur[((size_t)b * 256 + d) * NB_S + blk];
  if (!FINAL) for (int e = tid; e < 256 * NB_S; e += TPB) h2[e] = 0u;
  __syncthreads();

  for (unsigned t0 = s0; t0 < s1; t0 += 2048u) {
    // clear per-wave hist
    { uint4* w4 = (uint4*)&wh[0][0];
      for (int j = tid; j < 256; j += TPB) w4[j] = make_uint4(0u, 0u, 0u, 0u); }
    __syncthreads();

    // Phase A: rank within wave (order: wv, chunk, lane == memory order)
    unsigned key[8], idx[8], wloc[8];
    bool val[8];
    const unsigned wbase = t0 + (unsigned)wv * 512u;
#pragma unroll
    for (int c = 0; c < 8; ++c) {
      const unsigned i = wbase + (unsigned)c * 64u + (unsigned)lane;
      val[c] = (i < s1);
      uint2 r = val[c] ? in[i] : make_uint2(0u, 0u);
      idx[c] = r.x; key[c] = r.y;
      const unsigned dig = (key[c] >> shift) & 255u;
      unsigned long long peers = __ballot(val[c]);
#pragma unroll
      for (int bit = 0; bit < 8; ++bit) {
        unsigned long long bb = __ballot(val[c] && ((dig >> bit) & 1u));
        peers &= ((dig >> bit) & 1u) ? bb : ~bb;
      }
      const unsigned before = (unsigned)__popcll(peers & ltm);
      int ldr = __ffsll((unsigned long long)peers) - 1;
      if (ldr < 0) ldr = 0;
      unsigned old = 0;
      if (val[c] && lane == ldr) old = atomicAdd(&wh[wv][dig], (unsigned)__popcll(peers));
      old = __shfl(old, ldr, 64);
      wloc[c] = old + before;
    }
    __syncthreads();

    // Phase B: per-digit cross-wave prefix + in-tile bin starts + advance gbase
    {
      const unsigned d = (unsigned)tid;
      const unsigned w0 = wh[0][d], w1 = wh[1][d], w2 = wh[2][d], w3 = wh[3][d];
      const unsigned tot = w0 + w1 + w2 + w3;
      unsigned incl = tot;
      for (int off = 1; off < 64; off <<= 1) {
        unsigned t = __shfl_up(incl, off, 64);
        if (lane >= off) incl += t;
      }
      if (lane == 63) wsum[wv] = incl;
      __syncthreads();
      unsigned wpre = 0;
      for (int w = 0; w < wv; ++w) wpre += wsum[w];
      const unsigned tstart = incl - tot + wpre;
      const unsigned g = gbase[d];
      gout[d] = g - tstart;
      gbase[d] = g + tot;
      wh[0][d] = tstart;
      wh[1][d] = tstart + w0;
      wh[2][d] = tstart + w0 + w1;
      wh[3][d] = tstart + w0 + w1 + w2;
    }
    __syncthreads();

    // Phase C: stage records into LDS in digit order
#pragma unroll
    for (int c = 0; c < 8; ++c) {
      if (val[c]) {
        const unsigned dig = (key[c] >> shift) & 255u;
        uint2 r; r.x = idx[c]; r.y = key[c];
        stg[wh[wv][dig] + wloc[c]] = r;
      }
    }
    __syncthreads();

    // Phase D: coalesced write-out (or final fill)
    const unsigned nt = min(2048u, s1 - t0);
    for (unsigned j = tid; j < nt; j += TPB) {
      const uint2 r = stg[j];
      const unsigned dig = (r.y >> shift) & 255u;
      const unsigned pos = gout[dig] + j;
      if (!FINAL) {
        out[pos] = r;
        const unsigned nd = (r.y >> (shift + 8)) & 255u;
        atomicAdd(&h2[nd * NB_S + divCHS(pos)], 1u);
      } else {
        if (pos < (unsigned)KSEL) {
          const unsigned p = (unsigned)b * (unsigned)KSEL + pos;
          unsigned o0, o1;
          threefry2x32(0u, 42u, 0u, p, o0, o1);
          const unsigned bits = o0 ^ o1;
          const float u = __uint_as_float((bits >> 9) | 0x3f800000u) - 1.0f;
          const unsigned ch = r.x >> LOG_HW;
          const float lo = ((const float*)(ws + WS_MN))[b * CCH + ch];
          const float hi = ((const float*)(ws + WS_MX))[b * CCH + ch];
          outF[(size_t)b * NPS + r.x] = lo + u * (hi - lo);
        }
      }
    }
    __syncthreads();
  }

  if (!FINAL) {
    unsigned* Hb = Hnext + (size_t)b * 256 * NB_S;
    for (int e = tid; e < 256 * NB_S; e += TPB) {
      unsigned c = h2[e];
      if (c) atomicAdd(&Hb[e], c);
    }
  }
}

extern "C" void kernel_launch(void* const* d_in, const int* in_sizes, int n_in,
                              void* d_out, int out_size, void* d_ws, size_t ws_size,
                              hipStream_t stream) {
  const float* x = (const float*)d_in[0];
  const unsigned* gb = (const unsigned*)d_in[1];   // grad bits
  float* out = (float*)d_out;
  unsigned* ws = (unsigned*)d_ws;
  if (ws_size < WS_NEEDED_BYTES) return;

  uint2* bufA = (uint2*)(ws + WS_FIX_END);
  uint2* bufB = (uint2*)(ws + WS_FIX_END + RECW);
  unsigned* H0 = ws + WS_H0;
  unsigned* H1 = ws + WS_H1;
  unsigned* H2 = ws + WS_H2;
  unsigned* H3 = ws + WS_H3;

  dim3 blk(TPB);

  // 0. fused out=x copy + min/max partials ; zero hist region (THA..H3)
  k_copymn<<<dim3(BN * CCH * SUB), blk, 0, stream>>>((const float4*)x, (float4*)out, ws);
  k_mnfin<<<dim3(1), blk, 0, stream>>>(ws);
  {
    const int nz = (int)(WS_FIX_END - WS_THA);
    k_zero<<<dim3((nz + TPB - 1) / TPB), blk, 0, stream>>>(ws + WS_THA, nz);
  }

  // 1. exact K-th key G* via 11/11/10-bit histogram refinement
  k_thrA<<<dim3(NB_T, BN), blk, 0, stream>>>(gb, ws + WS_THA);
  k_find<<<dim3(BN), blk, 0, stream>>>(ws + WS_THA, ws, 0);
  k_thrBC<<<dim3(NB_T, BN), blk, 0, stream>>>(gb, ws + WS_THB, ws, 1);
  k_find<<<dim3(BN), blk, 0, stream>>>(ws + WS_THB, ws, 1);
  k_thrBC<<<dim3(NB_T, BN), blk, 0, stream>>>(gb, ws + WS_THC, ws, 2);
  k_find<<<dim3(BN), blk, 0, stream>>>(ws + WS_THC, ws, 2);

  // 2. index-ordered compaction (records) + fused pass-1 histogram
  k_ccount<<<dim3(NB_T, BN), blk, 0, stream>>>(gb, ws);
  k_cscan<<<dim3(BN), dim3(64), 0, stream>>>(ws);
  k_cscatter<<<dim3(NB_T, BN), blk, 0, stream>>>(gb, ws, bufA, H0);

  // 3. stable LSD radix sort, 4 x 8-bit, fused next-pass hists; final pass fills out
  k_hscan<<<dim3(BN), blk, 0, stream>>>(H0);
  k_sort8<0><<<dim3(NB_S, BN), blk, 0, stream>>>(bufA, bufB, H0, H1, ws, out, 0);
  k_hscan<<<dim3(BN), blk, 0, stream>>>(H1);
  k_sort8<0><<<dim3(NB_S, BN), blk, 0, stream>>>(bufB, bufA, H1, H2, ws, out, 8);
  k_hscan<<<dim3(BN), blk, 0, stream>>>(H2);
  k_sort8<0><<<dim3(NB_S, BN), blk, 0, stream>>>(bufA, bufB, H2, H3, ws, out, 16);
  k_hscan<<<dim3(BN), blk, 0, stream>>>(H3);
  k_sort8<1><<<dim3(NB_S, BN), blk, 0, stream>>>(bufB, bufA, H3, (unsigned*)nullptr, ws, out, 24);
}

// Round 4
// 817.425 us; speedup vs baseline: 2.8455x; 1.1109x over previous
//
#include <hip/hip_runtime.h>
#include <stdint.h>

#define TPB 256
#define TPS 1024          // threads per sort block

// Problem constants
constexpr int BN   = 64;          // batch
constexpr int CCH  = 3;           // channels
constexpr int HWS  = 262144;      // H*W
constexpr int LOG_HW = 18;
constexpr int NPS  = 786432;      // C*H*W per sample
constexpr int KSEL = 196608;      // K_UPPER
constexpr int KCAP = 200704;      // KSEL + slack for boundary-bin duplicates
constexpr int NB_T = 32;          // blocks/sample for full-N passes
constexpr int CH_T = NPS / NB_T;  // 24576
constexpr int NB_S = 4;           // blocks/sample for sort passes
constexpr int CH_S = KCAP / NB_S; // 50176
constexpr int TILE = 4096;        // records per sort tile (TPS * 4)
constexpr int NBINS = 2048;       // threshold-refinement bins
constexpr int SUB  = 8;           // sub-blocks per (b,c) in copy+mnmx

// ws layout (u32 offsets)
constexpr int WS_MN   = 0;        // f32[192]
constexpr int WS_MX   = 192;      // f32[192]
constexpr int WS_V1   = 384;
constexpr int WS_B1   = 448;
constexpr int WS_GS   = 640;      // inclusive key threshold G*
constexpr int WS_KP   = 704;      // compacted count per sample
constexpr int WS_CNT  = 768;      // u32[64*32]
constexpr int WS_COFF = 2816;     // u32[64*32]
constexpr int WS_MNP  = 4864;     // f32[1536] partial mins
constexpr int WS_MXP  = 6400;     // f32[1536] partial maxs
constexpr int WS_THA  = 8192;
constexpr int WS_THB  = WS_THA + BN * NBINS;          // 139264
constexpr int WS_H0   = WS_THB + BN * NBINS;          // 270336 ; u32[64][256][NB_S] per pass
constexpr int WS_H1   = WS_H0 + BN * 256 * NB_S;
constexpr int WS_H2   = WS_H1 + BN * 256 * NB_S;
constexpr int WS_H3   = WS_H2 + BN * 256 * NB_S;
constexpr size_t WS_FIX_END = (size_t)WS_H3 + (size_t)BN * 256 * NB_S;  // 532480 words
constexpr size_t RECW = (size_t)BN * KCAP * 2;        // words per uint2 record buffer
constexpr size_t WS_NEEDED_BYTES = (WS_FIX_END + 2 * RECW) * 4;   // ~207.7 MB

// ---------------- threefry2x32 (JAX-exact, partitionable stream) ----------------
__device__ __forceinline__ unsigned rotl32(unsigned x, int r) { return (x << r) | (x >> (32 - r)); }

__device__ __forceinline__ void tf4(unsigned& x0, unsigned& x1, int a, int b, int c, int d) {
  x0 += x1; x1 = rotl32(x1, a); x1 ^= x0;
  x0 += x1; x1 = rotl32(x1, b); x1 ^= x0;
  x0 += x1; x1 = rotl32(x1, c); x1 ^= x0;
  x0 += x1; x1 = rotl32(x1, d); x1 ^= x0;
}

__device__ __forceinline__ void threefry2x32(unsigned k0, unsigned k1, unsigned c0, unsigned c1,
                                             unsigned& o0, unsigned& o1) {
  const unsigned ks2 = k0 ^ k1 ^ 0x1BD11BDAu;
  unsigned x0 = c0 + k0, x1 = c1 + k1;
  tf4(x0, x1, 13, 15, 26, 6);  x0 += k1;  x1 += ks2 + 1u;
  tf4(x0, x1, 17, 29, 16, 24); x0 += ks2; x1 += k0 + 2u;
  tf4(x0, x1, 13, 15, 26, 6);  x0 += k0;  x1 += k1 + 3u;
  tf4(x0, x1, 17, 29, 16, 24); x0 += k1;  x1 += ks2 + 4u;
  tf4(x0, x1, 13, 15, 26, 6);  x0 += ks2; x1 += k0 + 5u;
  o0 = x0; o1 = x1;
}

// ---------------- kernels ----------------
__global__ __launch_bounds__(TPB) void k_zero(unsigned* __restrict__ p, int n) {
  int i = blockIdx.x * TPB + threadIdx.x;
  if (i < n) p[i] = 0u;
}

// fused out=x copy + per-(b,c) min/max partials (excluding channel's last element)
__global__ __launch_bounds__(TPB) void k_copymn(const float4* __restrict__ x,
                                                float4* __restrict__ o,
                                                unsigned* __restrict__ ws) {
  __shared__ float smn[TPB], smx[TPB];
  const int g = blockIdx.x;            // bc*SUB + sub
  const int bc = g / SUB, sub = g - bc * SUB;
  const int Q4 = HWS / 4 / SUB;        // 8192 float4 per sub-block
  const size_t base4 = (size_t)bc * (HWS / 4) + (size_t)sub * Q4;
  const bool last = (sub == SUB - 1);
  const int tid = threadIdx.x;
  float lo = 3.4e38f, hi = -3.4e38f;
  for (int i = tid; i < Q4; i += TPB) {
    float4 v = x[base4 + i];
    o[base4 + i] = v;
    if (last && i == Q4 - 1) {         // exclude final element of the channel
      lo = fminf(lo, fminf(fminf(v.x, v.y), v.z));
      hi = fmaxf(hi, fmaxf(fmaxf(v.x, v.y), v.z));
    } else {
      lo = fminf(lo, fminf(fminf(v.x, v.y), fminf(v.z, v.w)));
      hi = fmaxf(hi, fmaxf(fmaxf(v.x, v.y), fmaxf(v.z, v.w)));
    }
  }
  smn[tid] = lo; smx[tid] = hi; __syncthreads();
  for (int s = TPB / 2; s > 0; s >>= 1) {
    if (tid < s) { smn[tid] = fminf(smn[tid], smn[tid + s]); smx[tid] = fmaxf(smx[tid], smx[tid + s]); }
    __syncthreads();
  }
  if (tid == 0) {
    ((float*)(ws + WS_MNP))[g] = smn[0];
    ((float*)(ws + WS_MXP))[g] = smx[0];
  }
}

__global__ __launch_bounds__(TPB) void k_mnfin(unsigned* __restrict__ ws) {
  const int t = threadIdx.x;
  if (t < BN * CCH) {
    const float* mnp = (const float*)(ws + WS_MNP);
    const float* mxp = (const float*)(ws + WS_MXP);
    float lo = 3.4e38f, hi = -3.4e38f;
    for (int s = 0; s < SUB; ++s) {
      lo = fminf(lo, mnp[t * SUB + s]);
      hi = fmaxf(hi, mxp[t * SUB + s]);
    }
    ((float*)(ws + WS_MN))[t] = lo;
    ((float*)(ws + WS_MX))[t] = hi;
  }
}

__global__ __launch_bounds__(TPB) void k_thrA(const unsigned* __restrict__ gb, unsigned* __restrict__ hist) {
  __shared__ unsigned h[NBINS];
  const int b = blockIdx.y, blk = blockIdx.x, tid = threadIdx.x;
  for (int v = tid; v < NBINS; v += TPB) h[v] = 0u;
  __syncthreads();
  const uint4* g4 = (const uint4*)(gb + (size_t)b * NPS + (size_t)blk * CH_T);
  for (int i = tid; i < CH_T / 4; i += TPB) {
    uint4 v = g4[i];
    atomicAdd(&h[(v.x & 0x7FFFFFFFu) >> 21], 1u);
    atomicAdd(&h[(v.y & 0x7FFFFFFFu) >> 21], 1u);
    atomicAdd(&h[(v.z & 0x7FFFFFFFu) >> 21], 1u);
    atomicAdd(&h[(v.w & 0x7FFFFFFFu) >> 21], 1u);
  }
  __syncthreads();
  unsigned* gh = hist + (size_t)b * NBINS;
  for (int v = tid; v < NBINS; v += TPB) if (h[v]) atomicAdd(&gh[v], h[v]);
}

// second refinement round: among elements with top11==V1, histogram mid-11 bits
__global__ __launch_bounds__(TPB) void k_thrB(const unsigned* __restrict__ gb,
                                              unsigned* __restrict__ hist,
                                              const unsigned* __restrict__ ws) {
  __shared__ unsigned h[NBINS];
  const int b = blockIdx.y, blk = blockIdx.x, tid = threadIdx.x;
  for (int v = tid; v < NBINS; v += TPB) h[v] = 0u;
  __syncthreads();
  const unsigned sel = ws[WS_V1 + b];
  const uint4* g4 = (const uint4*)(gb + (size_t)b * NPS + (size_t)blk * CH_T);
  for (int i = tid; i < CH_T / 4; i += TPB) {
    uint4 v = g4[i];
    unsigned a0 = v.x & 0x7FFFFFFFu, a1 = v.y & 0x7FFFFFFFu;
    unsigned a2 = v.z & 0x7FFFFFFFu, a3 = v.w & 0x7FFFFFFFu;
    if ((a0 >> 21) == sel) atomicAdd(&h[(a0 >> 10) & 2047u], 1u);
    if ((a1 >> 21) == sel) atomicAdd(&h[(a1 >> 10) & 2047u], 1u);
    if ((a2 >> 21) == sel) atomicAdd(&h[(a2 >> 10) & 2047u], 1u);
    if ((a3 >> 21) == sel) atomicAdd(&h[(a3 >> 10) & 2047u], 1u);
  }
  __syncthreads();
  unsigned* gh = hist + (size_t)b * NBINS;
  for (int v = tid; v < NBINS; v += TPB) if (h[v]) atomicAdd(&gh[v], h[v]);
}

// mode 0: top 11 bits -> V1, B1 ; mode 1: mid 11 bits -> finalize G* (22-bit prefix), Kp
__global__ __launch_bounds__(TPB) void k_find(const unsigned* __restrict__ hist,
                                              unsigned* __restrict__ ws, int mode) {
  __shared__ unsigned part[TPB];
  const int b = blockIdx.x, tid = threadIdx.x;
  const unsigned* h = hist + (size_t)b * NBINS;
  const int per = NBINS / TPB;
  const unsigned Kt = (mode == 0) ? (unsigned)KSEL : (unsigned)KSEL - ws[WS_B1 + b];
  unsigned vals[8];
  unsigned s = 0;
  for (int j = 0; j < per; ++j) { vals[j] = h[tid * per + j]; s += vals[j]; }
  part[tid] = s; __syncthreads();
  for (int off = 1; off < TPB; off <<= 1) {
    unsigned t = (tid >= off) ? part[tid - off] : 0u;
    __syncthreads(); part[tid] += t; __syncthreads();
  }
  unsigned run = part[tid] - s;
  for (int j = 0; j < per; ++j) {
    const unsigned lo = run, c = vals[j];
    run += c;
    if (lo < Kt && Kt <= run) {
      const unsigned v = (unsigned)(tid * per + j);
      if (mode == 0) {
        ws[WS_V1 + b] = v; ws[WS_B1 + b] = lo;
      } else {
        const unsigned T22 = (ws[WS_V1 + b] << 11) | v;
        ws[WS_GS + b] = (T22 << 10) | 1023u;        // inclusive 31-bit threshold
        unsigned kp = ws[WS_B1 + b] + lo + c;       // countLess(T22) + countEq(T22)
        if (kp > (unsigned)KCAP) kp = (unsigned)KCAP;
        ws[WS_KP + b] = kp;
      }
    }
  }
}

__global__ __launch_bounds__(TPB) void k_ccount(const unsigned* __restrict__ gb, unsigned* __restrict__ ws) {
  __shared__ unsigned r[TPB];
  const int b = blockIdx.y, blk = blockIdx.x, tid = threadIdx.x;
  const unsigned G = ws[WS_GS + b];
  const uint4* g4 = (const uint4*)(gb + (size_t)b * NPS + (size_t)blk * CH_T);
  unsigned c = 0;
  for (int i = tid; i < CH_T / 4; i += TPB) {
    uint4 v = g4[i];
    c += (unsigned)((v.x & 0x7FFFFFFFu) <= G) + (unsigned)((v.y & 0x7FFFFFFFu) <= G)
       + (unsigned)((v.z & 0x7FFFFFFFu) <= G) + (unsigned)((v.w & 0x7FFFFFFFu) <= G);
  }
  r[tid] = c; __syncthreads();
  for (int s = TPB / 2; s > 0; s >>= 1) { if (tid < s) r[tid] += r[tid + s]; __syncthreads(); }
  if (tid == 0) ws[WS_CNT + b * NB_T + blk] = r[0];
}

__global__ void k_cscan(unsigned* __restrict__ ws) {
  const int b = blockIdx.x;
  if (threadIdx.x == 0) {
    unsigned run = 0;
    for (int j = 0; j < NB_T; ++j) {
      unsigned t = ws[WS_CNT + b * NB_T + j];
      ws[WS_COFF + b * NB_T + j] = run;
      run += t;
    }
  }
}

// index-ordered compaction of {i : key[i] <= G*} -> uint2(idx,key) records,
// fused pass-1 per-destblock digit histogram into H0.
__global__ __launch_bounds__(TPB) void k_cscatter(const unsigned* __restrict__ gb,
                                                  const unsigned* __restrict__ ws,
                                                  uint2* __restrict__ outR,
                                                  unsigned* __restrict__ H0) {
  __shared__ unsigned h2[256 * NB_S];   // 4 KB
  __shared__ unsigned waveTot[4];
  __shared__ unsigned runBase;
  const int b = blockIdx.y, blk = blockIdx.x, tid = threadIdx.x;
  const int lane = tid & 63, wv = tid >> 6;
  const unsigned long long ltm = (1ull << lane) - 1ull;
  const unsigned G = ws[WS_GS + b];
  for (int e = tid; e < 256 * NB_S; e += TPB) h2[e] = 0u;
  if (tid == 0) runBase = ws[WS_COFF + b * NB_T + blk];
  __syncthreads();
  const unsigned* g = gb + (size_t)b * NPS;
  uint2* oR = outR + (size_t)b * KCAP;
  const unsigned c0 = (unsigned)blk * CH_T;
  for (int t = 0; t < CH_T / 1024; ++t) {
    const unsigned base = c0 + (unsigned)t * 1024u + (unsigned)wv * 256u;
    unsigned key[4], wloc[4];
    bool sel[4];
    unsigned run = 0;
#pragma unroll
    for (int c = 0; c < 4; ++c) {
      const unsigned i = base + (unsigned)c * 64u + (unsigned)lane;
      key[c] = g[i] & 0x7FFFFFFFu;
      sel[c] = (key[c] <= G);
      unsigned long long m = __ballot(sel[c]);
      wloc[c] = run + (unsigned)__popcll(m & ltm);
      run += (unsigned)__popcll(m);
    }
    if (lane == 0) waveTot[wv] = run;
    __syncthreads();
    unsigned wpre = 0;
    for (int w = 0; w < wv; ++w) wpre += waveTot[w];
    const unsigned rb = runBase;
#pragma unroll
    for (int c = 0; c < 4; ++c) {
      if (sel[c]) {
        const unsigned pos = rb + wpre + wloc[c];
        if (pos < (unsigned)KCAP) {
          const unsigned i = base + (unsigned)c * 64u + (unsigned)lane;
          uint2 r; r.x = i; r.y = key[c];
          oR[pos] = r;
          atomicAdd(&h2[(key[c] & 255u) * NB_S + pos / (unsigned)CH_S], 1u);
        }
      }
    }
    __syncthreads();
    if (tid == 0) runBase += waveTot[0] + waveTot[1] + waveTot[2] + waveTot[3];
  }
  __syncthreads();
  unsigned* Hb = H0 + (size_t)b * 256 * NB_S;
  for (int e = tid; e < 256 * NB_S; e += TPB) {
    unsigned c = h2[e];
    if (c) atomicAdd(&Hb[e], c);
  }
}

// per-sample scan of H[b][256][NB_S] counts -> global output bases (lexicographic dig,blk)
__global__ __launch_bounds__(TPB) void k_hscan(unsigned* __restrict__ H) {
  __shared__ unsigned wsum[4];
  const int b = blockIdx.x, tid = threadIdx.x;
  const int lane = tid & 63, wv = tid >> 6;
  unsigned* Hb = H + (size_t)b * 256 * NB_S;
  unsigned row[NB_S];
  unsigned run = 0;
#pragma unroll
  for (int k = 0; k < NB_S; ++k) {
    unsigned t = Hb[tid * NB_S + k];
    row[k] = run; run += t;
  }
  unsigned incl = run;
  for (int off = 1; off < 64; off <<= 1) {
    unsigned t = __shfl_up(incl, off, 64);
    if (lane >= off) incl += t;
  }
  if (lane == 63) wsum[wv] = incl;
  __syncthreads();
  unsigned wpre = 0;
  for (int w = 0; w < wv; ++w) wpre += wsum[w];
  const unsigned excl = incl - run + wpre;
#pragma unroll
  for (int k = 0; k < NB_S; ++k) Hb[tid * NB_S + k] = row[k] + excl;
}

// One stable 8-bit LSD radix pass, TPS=1024 threads, tile=4096 records.
// FINAL=0: LDS-staged coalesced record write + fused next-pass histogram.
// FINAL=1: rank computed inline (no staging) -> threefry fill into outF.
template<int FINAL>
__global__ __launch_bounds__(TPS) void k_sort8(const uint2* __restrict__ inR,
                                               uint2* __restrict__ outR,
                                               const unsigned* __restrict__ Hcur,
                                               unsigned* __restrict__ Hnext,
                                               const unsigned* __restrict__ ws,
                                               float* __restrict__ outF,
                                               int shift) {
  __shared__ unsigned wh[16][256];       // per-wave digit counts -> per-wave in-tile bases
  __shared__ unsigned gout[256];         // gbase[d] - tstart[d] (tile-local -> global)
  __shared__ unsigned gbase[256];        // running global base per digit
  __shared__ unsigned wsum[4];
  __shared__ uint2    stg[FINAL ? 1 : TILE];     // staged tile (non-final only)
  __shared__ unsigned h2[FINAL ? 1 : 256 * NB_S];
  const int b = blockIdx.y, blk = blockIdx.x, tid = threadIdx.x;
  const int lane = tid & 63, wv = tid >> 6;
  const unsigned long long ltm = (1ull << lane) - 1ull;
  const unsigned kp = min(ws[WS_KP + b], (unsigned)KCAP);
  const unsigned s0 = (unsigned)blk * CH_S;
  const unsigned s1 = min(s0 + (unsigned)CH_S, kp);
  const uint2* in = inR + (size_t)b * KCAP;
  uint2* out = outR + (size_t)b * KCAP;

  for (int d = tid; d < 256; d += TPS) gbase[d] = Hcur[((size_t)b * 256 + d) * NB_S + blk];
  if (!FINAL) for (int e = tid; e < 256 * NB_S; e += TPS) h2[e] = 0u;
  __syncthreads();

  for (unsigned t0 = s0; t0 < s1; t0 += (unsigned)TILE) {
    // clear per-wave hist: 16*256 = 4096 words = 1024 uint4
    { uint4* w4 = (uint4*)&wh[0][0];
      w4[tid] = make_uint4(0u, 0u, 0u, 0u); }
    __syncthreads();

    // Phase A: rank within wave (order: wv, chunk, lane == memory order)
    unsigned key[4], idx[4], wloc[4], dig[4];
    bool val[4];
    const unsigned wbase = t0 + (unsigned)wv * 256u;
#pragma unroll
    for (int c = 0; c < 4; ++c) {
      const unsigned i = wbase + (unsigned)c * 64u + (unsigned)lane;
      val[c] = (i < s1);
      uint2 r = val[c] ? in[i] : make_uint2(0u, 0u);
      idx[c] = r.x; key[c] = r.y;
      dig[c] = (key[c] >> shift) & 255u;
      unsigned long long peers = __ballot(val[c]);
#pragma unroll
      for (int bit = 0; bit < 8; ++bit) {
        unsigned long long bb = __ballot(val[c] && ((dig[c] >> bit) & 1u));
        peers &= ((dig[c] >> bit) & 1u) ? bb : ~bb;
      }
      const unsigned before = (unsigned)__popcll(peers & ltm);
      int ldr = __ffsll((unsigned long long)peers) - 1;
      if (ldr < 0) ldr = 0;
      unsigned old = 0;
      if (val[c] && lane == ldr) old = atomicAdd(&wh[wv][dig[c]], (unsigned)__popcll(peers));
      old = __shfl(old, ldr, 64);
      wloc[c] = old + before;
    }
    __syncthreads();

    // Phase B: per-digit cross-wave prefix + tile bin starts + advance gbase
    unsigned incl = 0, tot = 0;
    if (tid < 256) {
      const unsigned d = (unsigned)tid;
#pragma unroll
      for (int w = 0; w < 16; ++w) tot += wh[w][d];
      incl = tot;
      for (int off = 1; off < 64; off <<= 1) {
        unsigned t = __shfl_up(incl, off, 64);
        if (lane >= off) incl += t;
      }
      if (lane == 63) wsum[wv] = incl;   // wv in 0..3 here
    }
    __syncthreads();
    if (tid < 256) {
      const unsigned d = (unsigned)tid;
      unsigned wpre = 0;
      for (int w = 0; w < wv; ++w) wpre += wsum[w];
      const unsigned tstart = incl - tot + wpre;
      const unsigned g = gbase[d];
      gout[d] = g - tstart;
      gbase[d] = g + tot;
      unsigned run = tstart;
#pragma unroll
      for (int w = 0; w < 16; ++w) { const unsigned t = wh[w][d]; wh[w][d] = run; run += t; }
    }
    __syncthreads();

    if (!FINAL) {
      // Phase C: stage records into LDS in digit order
#pragma unroll
      for (int c = 0; c < 4; ++c) {
        if (val[c]) {
          uint2 r; r.x = idx[c]; r.y = key[c];
          stg[wh[wv][dig[c]] + wloc[c]] = r;
        }
      }
      __syncthreads();
      // Phase D: coalesced write-out + fused next-pass histogram
      const unsigned nt = min((unsigned)TILE, s1 - t0);
      for (unsigned j = tid; j < nt; j += TPS) {
        const uint2 r = stg[j];
        const unsigned d = (r.y >> shift) & 255u;
        const unsigned pos = gout[d] + j;
        out[pos] = r;
        const unsigned nd = (r.y >> (shift + 8)) & 255u;
        atomicAdd(&h2[nd * NB_S + pos / (unsigned)CH_S], 1u);
      }
    } else {
      // Final pass: rank inline, fill out
#pragma unroll
      for (int c = 0; c < 4; ++c) {
        if (val[c]) {
          const unsigned rank = gout[dig[c]] + wh[wv][dig[c]] + wloc[c];
          if (rank < (unsigned)KSEL) {
            const unsigned p = (unsigned)b * (unsigned)KSEL + rank;
            unsigned o0, o1;
            threefry2x32(0u, 42u, 0u, p, o0, o1);
            const unsigned bits = o0 ^ o1;
            const float u = __uint_as_float((bits >> 9) | 0x3f800000u) - 1.0f;
            const unsigned ch = idx[c] >> LOG_HW;
            const float lo = ((const float*)(ws + WS_MN))[b * CCH + ch];
            const float hi = ((const float*)(ws + WS_MX))[b * CCH + ch];
            outF[(size_t)b * NPS + idx[c]] = lo + u * (hi - lo);
          }
        }
      }
    }
    __syncthreads();   // protect wh/gout/gbase before next tile's clear
  }

  if (!FINAL) {
    unsigned* Hb = Hnext + (size_t)b * 256 * NB_S;
    for (int e = tid; e < 256 * NB_S; e += TPS) {
      unsigned c = h2[e];
      if (c) atomicAdd(&Hb[e], c);
    }
  }
}

extern "C" void kernel_launch(void* const* d_in, const int* in_sizes, int n_in,
                              void* d_out, int out_size, void* d_ws, size_t ws_size,
                              hipStream_t stream) {
  const float* x = (const float*)d_in[0];
  const unsigned* gb = (const unsigned*)d_in[1];   // grad bits
  float* out = (float*)d_out;
  unsigned* ws = (unsigned*)d_ws;
  if (ws_size < WS_NEEDED_BYTES) return;

  uint2* bufA = (uint2*)(ws + WS_FIX_END);
  uint2* bufB = (uint2*)(ws + WS_FIX_END + RECW);
  unsigned* H0 = ws + WS_H0;
  unsigned* H1 = ws + WS_H1;
  unsigned* H2 = ws + WS_H2;
  unsigned* H3 = ws + WS_H3;

  dim3 blk(TPB);
  dim3 sblk(TPS);

  // 0. fused out=x copy + min/max partials ; zero hist region (THA..FIX_END)
  k_copymn<<<dim3(BN * CCH * SUB), blk, 0, stream>>>((const float4*)x, (float4*)out, ws);
  k_mnfin<<<dim3(1), blk, 0, stream>>>(ws);
  {
    const int nz = (int)(WS_FIX_END - WS_THA);
    k_zero<<<dim3((nz + TPB - 1) / TPB), blk, 0, stream>>>(ws + WS_THA, nz);
  }

  // 1. 22-bit prefix threshold via 11+11-bit histogram refinement
  k_thrA<<<dim3(NB_T, BN), blk, 0, stream>>>(gb, ws + WS_THA);
  k_find<<<dim3(BN), blk, 0, stream>>>(ws + WS_THA, ws, 0);
  k_thrB<<<dim3(NB_T, BN), blk, 0, stream>>>(gb, ws + WS_THB, ws);
  k_find<<<dim3(BN), blk, 0, stream>>>(ws + WS_THB, ws, 1);

  // 2. index-ordered compaction (records) + fused pass-1 histogram
  k_ccount<<<dim3(NB_T, BN), blk, 0, stream>>>(gb, ws);
  k_cscan<<<dim3(BN), dim3(64), 0, stream>>>(ws);
  k_cscatter<<<dim3(NB_T, BN), blk, 0, stream>>>(gb, ws, bufA, H0);

  // 3. stable LSD radix sort, 4 x 8-bit, fused next-pass hists; final pass fills out
  k_hscan<<<dim3(BN), blk, 0, stream>>>(H0);
  k_sort8<0><<<dim3(NB_S, BN), sblk, 0, stream>>>(bufA, bufB, H0, H1, ws, out, 0);
  k_hscan<<<dim3(BN), blk, 0, stream>>>(H1);
  k_sort8<0><<<dim3(NB_S, BN), sblk, 0, stream>>>(bufB, bufA, H1, H2, ws, out, 8);
  k_hscan<<<dim3(BN), blk, 0, stream>>>(H2);
  k_sort8<0><<<dim3(NB_S, BN), sblk, 0, stream>>>(bufA, bufB, H2, H3, ws, out, 16);
  k_hscan<<<dim3(BN), blk, 0, stream>>>(H3);
  k_sort8<1><<<dim3(NB_S, BN), sblk, 0, stream>>>(bufB, (uint2*)nullptr, H3, (unsigned*)nullptr, ws, out, 24);
}

// Round 5
// 798.225 us; speedup vs baseline: 2.9139x; 1.0241x over previous
//
#include <hip/hip_runtime.h>
#include <stdint.h>

#define TPB 256
#define TPS 1024          // threads per sort block

// Problem constants
constexpr int BN   = 64;          // batch
constexpr int CCH  = 3;           // channels
constexpr int HWS  = 262144;      // H*W
constexpr int LOG_HW = 18;
constexpr int NPS  = 786432;      // C*H*W per sample
constexpr int KSEL = 196608;      // K_UPPER
constexpr int KCAP = 200704;      // KSEL + slack for boundary-bin duplicates
constexpr int NB_T = 32;          // blocks/sample for threshold scans
constexpr int CH_T = NPS / NB_T;  // 24576
constexpr int NB_C = 64;          // blocks/sample for compaction/fill scans
constexpr int CH_C = NPS / NB_C;  // 12288
constexpr int NB_S = 8;           // blocks/sample for sort passes
constexpr int CH_S = KCAP / NB_S; // 25088
constexpr int TILE = 4096;        // records per sort tile (TPS * 4)
constexpr int NBINS = 2048;       // threshold-refinement bins
constexpr int SUB  = 8;           // sub-blocks per (b,c) in mnmx

// ws layout (u32 offsets)
constexpr int WS_MN   = 0;        // f32[192]
constexpr int WS_MX   = 192;      // f32[192]
constexpr int WS_V1   = 384;      // u32[64]
constexpr int WS_B1   = 448;      // u32[64]
constexpr int WS_GS   = 512;      // u32[64] inclusive key threshold G*
constexpr int WS_KP   = 576;      // u32[64] compacted count per sample
constexpr int WS_CNT  = 640;      // u32[64*64]
constexpr int WS_COFF = WS_CNT + BN * NB_C;      // 4736
constexpr int WS_MNP  = WS_COFF + BN * NB_C;     // 8832 ; f32[1536]
constexpr int WS_MXP  = WS_MNP + BN * CCH * SUB; // 10368 ; f32[1536]
constexpr int WS_THA  = WS_MXP + BN * CCH * SUB; // 11904
constexpr int WS_THB  = WS_THA + BN * NBINS;     // 142976
constexpr int WS_H0   = WS_THB + BN * NBINS;     // 274048 ; u32[64][256][NB_S]
constexpr int WS_H1   = WS_H0 + BN * 256 * NB_S;
constexpr int WS_H2   = WS_H1 + BN * 256 * NB_S;
constexpr int WS_H3   = WS_H2 + BN * 256 * NB_S;
constexpr size_t WS_FIX_END = (size_t)WS_H3 + (size_t)BN * 256 * NB_S;  // 929408 words
constexpr size_t RECW = (size_t)BN * KCAP * 2;   // words per uint2 record buffer
constexpr size_t WS_NEEDED_BYTES = (WS_FIX_END + 2 * RECW) * 4;   // 209.2 MB (proven-safe)

// ---------------- threefry2x32 (JAX-exact, partitionable stream) ----------------
__device__ __forceinline__ unsigned rotl32(unsigned x, int r) { return (x << r) | (x >> (32 - r)); }

__device__ __forceinline__ void tf4(unsigned& x0, unsigned& x1, int a, int b, int c, int d) {
  x0 += x1; x1 = rotl32(x1, a); x1 ^= x0;
  x0 += x1; x1 = rotl32(x1, b); x1 ^= x0;
  x0 += x1; x1 = rotl32(x1, c); x1 ^= x0;
  x0 += x1; x1 = rotl32(x1, d); x1 ^= x0;
}

__device__ __forceinline__ void threefry2x32(unsigned k0, unsigned k1, unsigned c0, unsigned c1,
                                             unsigned& o0, unsigned& o1) {
  const unsigned ks2 = k0 ^ k1 ^ 0x1BD11BDAu;
  unsigned x0 = c0 + k0, x1 = c1 + k1;
  tf4(x0, x1, 13, 15, 26, 6);  x0 += k1;  x1 += ks2 + 1u;
  tf4(x0, x1, 17, 29, 16, 24); x0 += ks2; x1 += k0 + 2u;
  tf4(x0, x1, 13, 15, 26, 6);  x0 += k0;  x1 += k1 + 3u;
  tf4(x0, x1, 17, 29, 16, 24); x0 += k1;  x1 += ks2 + 4u;
  tf4(x0, x1, 13, 15, 26, 6);  x0 += ks2; x1 += k0 + 5u;
  o0 = x0; o1 = x1;
}

// ---------------- kernels ----------------
__global__ __launch_bounds__(TPB) void k_zero(unsigned* __restrict__ p, int n) {
  int i = blockIdx.x * TPB + threadIdx.x;
  if (i < n) p[i] = 0u;
}

// per-(b,c) min/max partials (excluding channel's last element) — read-only
__global__ __launch_bounds__(TPB) void k_mnmx(const float4* __restrict__ x,
                                              unsigned* __restrict__ ws) {
  __shared__ float smn[TPB], smx[TPB];
  const int g = blockIdx.x;            // bc*SUB + sub
  const int bc = g / SUB, sub = g - bc * SUB;
  const int Q4 = HWS / 4 / SUB;        // 8192 float4 per sub-block
  const size_t base4 = (size_t)bc * (HWS / 4) + (size_t)sub * Q4;
  const bool last = (sub == SUB - 1);
  const int tid = threadIdx.x;
  float lo = 3.4e38f, hi = -3.4e38f;
  for (int i = tid; i < Q4; i += TPB) {
    float4 v = x[base4 + i];
    if (last && i == Q4 - 1) {         // exclude final element of the channel
      lo = fminf(lo, fminf(fminf(v.x, v.y), v.z));
      hi = fmaxf(hi, fmaxf(fmaxf(v.x, v.y), v.z));
    } else {
      lo = fminf(lo, fminf(fminf(v.x, v.y), fminf(v.z, v.w)));
      hi = fmaxf(hi, fmaxf(fmaxf(v.x, v.y), fmaxf(v.z, v.w)));
    }
  }
  smn[tid] = lo; smx[tid] = hi; __syncthreads();
  for (int s = TPB / 2; s > 0; s >>= 1) {
    if (tid < s) { smn[tid] = fminf(smn[tid], smn[tid + s]); smx[tid] = fmaxf(smx[tid], smx[tid + s]); }
    __syncthreads();
  }
  if (tid == 0) {
    ((float*)(ws + WS_MNP))[g] = smn[0];
    ((float*)(ws + WS_MXP))[g] = smx[0];
  }
}

__global__ __launch_bounds__(TPB) void k_mnfin(unsigned* __restrict__ ws) {
  const int t = threadIdx.x;
  if (t < BN * CCH) {
    const float* mnp = (const float*)(ws + WS_MNP);
    const float* mxp = (const float*)(ws + WS_MXP);
    float lo = 3.4e38f, hi = -3.4e38f;
    for (int s = 0; s < SUB; ++s) {
      lo = fminf(lo, mnp[t * SUB + s]);
      hi = fmaxf(hi, mxp[t * SUB + s]);
    }
    ((float*)(ws + WS_MN))[t] = lo;
    ((float*)(ws + WS_MX))[t] = hi;
  }
}

__global__ __launch_bounds__(TPB) void k_thrA(const unsigned* __restrict__ gb, unsigned* __restrict__ hist) {
  __shared__ unsigned h[NBINS];
  const int b = blockIdx.y, blk = blockIdx.x, tid = threadIdx.x;
  for (int v = tid; v < NBINS; v += TPB) h[v] = 0u;
  __syncthreads();
  const uint4* g4 = (const uint4*)(gb + (size_t)b * NPS + (size_t)blk * CH_T);
  for (int i = tid; i < CH_T / 4; i += TPB) {
    uint4 v = g4[i];
    atomicAdd(&h[(v.x & 0x7FFFFFFFu) >> 21], 1u);
    atomicAdd(&h[(v.y & 0x7FFFFFFFu) >> 21], 1u);
    atomicAdd(&h[(v.z & 0x7FFFFFFFu) >> 21], 1u);
    atomicAdd(&h[(v.w & 0x7FFFFFFFu) >> 21], 1u);
  }
  __syncthreads();
  unsigned* gh = hist + (size_t)b * NBINS;
  for (int v = tid; v < NBINS; v += TPB) if (h[v]) atomicAdd(&gh[v], h[v]);
}

// second refinement round: among elements with top11==V1, histogram mid-11 bits
__global__ __launch_bounds__(TPB) void k_thrB(const unsigned* __restrict__ gb,
                                              unsigned* __restrict__ hist,
                                              const unsigned* __restrict__ ws) {
  __shared__ unsigned h[NBINS];
  const int b = blockIdx.y, blk = blockIdx.x, tid = threadIdx.x;
  for (int v = tid; v < NBINS; v += TPB) h[v] = 0u;
  __syncthreads();
  const unsigned sel = ws[WS_V1 + b];
  const uint4* g4 = (const uint4*)(gb + (size_t)b * NPS + (size_t)blk * CH_T);
  for (int i = tid; i < CH_T / 4; i += TPB) {
    uint4 v = g4[i];
    unsigned a0 = v.x & 0x7FFFFFFFu, a1 = v.y & 0x7FFFFFFFu;
    unsigned a2 = v.z & 0x7FFFFFFFu, a3 = v.w & 0x7FFFFFFFu;
    if ((a0 >> 21) == sel) atomicAdd(&h[(a0 >> 10) & 2047u], 1u);
    if ((a1 >> 21) == sel) atomicAdd(&h[(a1 >> 10) & 2047u], 1u);
    if ((a2 >> 21) == sel) atomicAdd(&h[(a2 >> 10) & 2047u], 1u);
    if ((a3 >> 21) == sel) atomicAdd(&h[(a3 >> 10) & 2047u], 1u);
  }
  __syncthreads();
  unsigned* gh = hist + (size_t)b * NBINS;
  for (int v = tid; v < NBINS; v += TPB) if (h[v]) atomicAdd(&gh[v], h[v]);
}

// mode 0: top 11 bits -> V1, B1 ; mode 1: mid 11 bits -> finalize G* (22-bit prefix), Kp
__global__ __launch_bounds__(TPB) void k_find(const unsigned* __restrict__ hist,
                                              unsigned* __restrict__ ws, int mode) {
  __shared__ unsigned part[TPB];
  const int b = blockIdx.x, tid = threadIdx.x;
  const unsigned* h = hist + (size_t)b * NBINS;
  const int per = NBINS / TPB;
  const unsigned Kt = (mode == 0) ? (unsigned)KSEL : (unsigned)KSEL - ws[WS_B1 + b];
  unsigned vals[8];
  unsigned s = 0;
  for (int j = 0; j < per; ++j) { vals[j] = h[tid * per + j]; s += vals[j]; }
  part[tid] = s; __syncthreads();
  for (int off = 1; off < TPB; off <<= 1) {
    unsigned t = (tid >= off) ? part[tid - off] : 0u;
    __syncthreads(); part[tid] += t; __syncthreads();
  }
  unsigned run = part[tid] - s;
  for (int j = 0; j < per; ++j) {
    const unsigned lo = run, c = vals[j];
    run += c;
    if (lo < Kt && Kt <= run) {
      const unsigned v = (unsigned)(tid * per + j);
      if (mode == 0) {
        ws[WS_V1 + b] = v; ws[WS_B1 + b] = lo;
      } else {
        const unsigned T22 = (ws[WS_V1 + b] << 11) | v;
        ws[WS_GS + b] = (T22 << 10) | 1023u;        // inclusive 31-bit threshold
        unsigned kp = ws[WS_B1 + b] + lo + c;       // countLess(T22) + countEq(T22)
        if (kp > (unsigned)KCAP) kp = (unsigned)KCAP;
        ws[WS_KP + b] = kp;
      }
    }
  }
}

__global__ __launch_bounds__(TPB) void k_ccount(const unsigned* __restrict__ gb, unsigned* __restrict__ ws) {
  __shared__ unsigned r[TPB];
  const int b = blockIdx.y, blk = blockIdx.x, tid = threadIdx.x;
  const unsigned G = ws[WS_GS + b];
  const uint4* g4 = (const uint4*)(gb + (size_t)b * NPS + (size_t)blk * CH_C);
  unsigned c = 0;
  for (int i = tid; i < CH_C / 4; i += TPB) {
    uint4 v = g4[i];
    c += (unsigned)((v.x & 0x7FFFFFFFu) <= G) + (unsigned)((v.y & 0x7FFFFFFFu) <= G)
       + (unsigned)((v.z & 0x7FFFFFFFu) <= G) + (unsigned)((v.w & 0x7FFFFFFFu) <= G);
  }
  r[tid] = c; __syncthreads();
  for (int s = TPB / 2; s > 0; s >>= 1) { if (tid < s) r[tid] += r[tid + s]; __syncthreads(); }
  if (tid == 0) ws[WS_CNT + b * NB_C + blk] = r[0];
}

__global__ void k_cscan(unsigned* __restrict__ ws) {
  const int b = blockIdx.x;
  if (threadIdx.x == 0) {
    unsigned run = 0;
    for (int j = 0; j < NB_C; ++j) {
      unsigned t = ws[WS_CNT + b * NB_C + j];
      ws[WS_COFF + b * NB_C + j] = run;
      run += t;
    }
  }
}

// Index-ordered compaction of {i : key[i] <= G*} -> 4B key array (comppos == slot),
// fused pass-1 per-destblock digit histogram into H0. uint4 loads, per-lane prefix.
__global__ __launch_bounds__(TPB) void k_cscatter(const unsigned* __restrict__ gb,
                                                  const unsigned* __restrict__ ws,
                                                  unsigned* __restrict__ keyArr,
                                                  unsigned* __restrict__ H0) {
  __shared__ unsigned h2[256 * NB_S];   // 8 KB
  __shared__ unsigned waveTot[4];
  __shared__ unsigned runBase;
  const int b = blockIdx.y, blk = blockIdx.x, tid = threadIdx.x;
  const int lane = tid & 63, wv = tid >> 6;
  const unsigned G = ws[WS_GS + b];
  for (int e = tid; e < 256 * NB_S; e += TPB) h2[e] = 0u;
  if (tid == 0) runBase = ws[WS_COFF + b * NB_C + blk];
  __syncthreads();
  const uint4* g4 = (const uint4*)(gb + (size_t)b * NPS + (size_t)blk * CH_C);
  unsigned* ka = keyArr + (size_t)b * KCAP;
  for (int t = 0; t < CH_C / 1024; ++t) {              // 12 iters of 1024 elems
    const uint4 v = g4[t * 256 + tid];
    unsigned k[4] = { v.x & 0x7FFFFFFFu, v.y & 0x7FFFFFFFu, v.z & 0x7FFFFFFFu, v.w & 0x7FFFFFFFu };
    bool s[4];
    unsigned cnt = 0;
#pragma unroll
    for (int c = 0; c < 4; ++c) { s[c] = (k[c] <= G); cnt += (unsigned)s[c]; }
    unsigned incl = cnt;
    for (int off = 1; off < 64; off <<= 1) {
      unsigned u = __shfl_up(incl, off, 64);
      if (lane >= off) incl += u;
    }
    if (lane == 63) waveTot[wv] = incl;
    __syncthreads();
    const unsigned wt0 = waveTot[0], wt1 = waveTot[1], wt2 = waveTot[2], wt3 = waveTot[3];
    unsigned wpre = 0;
    if (wv > 0) wpre += wt0;
    if (wv > 1) wpre += wt1;
    if (wv > 2) wpre += wt2;
    unsigned pos = runBase + wpre + (incl - cnt);
#pragma unroll
    for (int c = 0; c < 4; ++c) {
      if (s[c]) {
        if (pos < (unsigned)KCAP) {
          ka[pos] = k[c];
          atomicAdd(&h2[(k[c] & 255u) * NB_S + pos / (unsigned)CH_S], 1u);
        }
        ++pos;
      }
    }
    __syncthreads();
    if (tid == 0) runBase += wt0 + wt1 + wt2 + wt3;
  }
  __syncthreads();
  unsigned* Hb = H0 + (size_t)b * 256 * NB_S;
  for (int e = tid; e < 256 * NB_S; e += TPB) {
    unsigned c = h2[e];
    if (c) atomicAdd(&Hb[e], c);
  }
}

// per-sample scan of H[b][256][NB_S] counts -> global output bases (lexicographic dig,blk)
__global__ __launch_bounds__(TPB) void k_hscan(unsigned* __restrict__ H) {
  __shared__ unsigned wsum[4];
  const int b = blockIdx.x, tid = threadIdx.x;
  const int lane = tid & 63, wv = tid >> 6;
  unsigned* Hb = H + (size_t)b * 256 * NB_S;
  unsigned row[NB_S];
  unsigned run = 0;
#pragma unroll
  for (int k = 0; k < NB_S; ++k) {
    unsigned t = Hb[tid * NB_S + k];
    row[k] = run; run += t;
  }
  unsigned incl = run;
  for (int off = 1; off < 64; off <<= 1) {
    unsigned t = __shfl_up(incl, off, 64);
    if (lane >= off) incl += t;
  }
  if (lane == 63) wsum[wv] = incl;
  __syncthreads();
  unsigned wpre = 0;
  for (int w = 0; w < wv; ++w) wpre += wsum[w];
  const unsigned excl = incl - run + wpre;
#pragma unroll
  for (int k = 0; k < NB_S; ++k) Hb[tid * NB_S + k] = row[k] + excl;
}

// One stable 8-bit LSD radix pass, TPS=1024 threads, tile=4096 records.
// MODE 0: input = 4B key array (comppos == position) -> records + next hist.
// MODE 1: records -> records + next hist (LDS-staged coalesced output).
// MODE 2: final: rank inline -> fillmap[comppos] = rank (or ~0u if rank >= KSEL).
template<int MODE>
__global__ __launch_bounds__(TPS) void k_sort8(const unsigned* __restrict__ keyIn,
                                               const uint2* __restrict__ inR,
                                               uint2* __restrict__ outR,
                                               unsigned* __restrict__ fillmap,
                                               const unsigned* __restrict__ Hcur,
                                               unsigned* __restrict__ Hnext,
                                               const unsigned* __restrict__ ws,
                                               int shift) {
  __shared__ unsigned wh[16][256];       // per-wave digit counts -> per-wave in-tile bases
  __shared__ unsigned gout[256];         // gbase[d] - tstart[d] (tile-local -> global)
  __shared__ unsigned gbase[256];        // running global base per digit
  __shared__ unsigned wsum[4];
  __shared__ uint2    stg[(MODE == 2) ? 1 : TILE];
  __shared__ unsigned h2[(MODE == 2) ? 1 : 256 * NB_S];
  const int b = blockIdx.y, blk = blockIdx.x, tid = threadIdx.x;
  const int lane = tid & 63, wv = tid >> 6;
  const unsigned long long ltm = (1ull << lane) - 1ull;
  const unsigned kp = min(ws[WS_KP + b], (unsigned)KCAP);
  const unsigned s0 = (unsigned)blk * CH_S;
  const unsigned s1 = min(s0 + (unsigned)CH_S, kp);
  const unsigned* ki = keyIn + (size_t)b * KCAP;
  const uint2* in = inR + (size_t)b * KCAP;
  uint2* out = outR + (size_t)b * KCAP;
  unsigned* fm = fillmap + (size_t)b * KCAP;

  for (int d = tid; d < 256; d += TPS) gbase[d] = Hcur[((size_t)b * 256 + d) * NB_S + blk];
  if (MODE != 2) for (int e = tid; e < 256 * NB_S; e += TPS) h2[e] = 0u;
  __syncthreads();

  for (unsigned t0 = s0; t0 < s1; t0 += (unsigned)TILE) {
    { uint4* w4 = (uint4*)&wh[0][0];
      w4[tid] = make_uint4(0u, 0u, 0u, 0u); }
    __syncthreads();

    // Phase A: rank within wave (order: wv, chunk, lane == memory order)
    unsigned key[4], cpp[4], wloc[4], dig[4];
    bool val[4];
    const unsigned wbase = t0 + (unsigned)wv * 256u;
#pragma unroll
    for (int c = 0; c < 4; ++c) {
      const unsigned i = wbase + (unsigned)c * 64u + (unsigned)lane;
      val[c] = (i < s1);
      if (MODE == 0) { cpp[c] = i; key[c] = val[c] ? ki[i] : 0u; }
      else { uint2 r = val[c] ? in[i] : make_uint2(0u, 0u); cpp[c] = r.x; key[c] = r.y; }
      dig[c] = (key[c] >> shift) & 255u;
      unsigned long long peers = __ballot(val[c]);
#pragma unroll
      for (int bit = 0; bit < 8; ++bit) {
        unsigned long long bb = __ballot(val[c] && ((dig[c] >> bit) & 1u));
        peers &= ((dig[c] >> bit) & 1u) ? bb : ~bb;
      }
      const unsigned before = (unsigned)__popcll(peers & ltm);
      int ldr = __ffsll((unsigned long long)peers) - 1;
      if (ldr < 0) ldr = 0;
      unsigned old = 0;
      if (val[c] && lane == ldr) old = atomicAdd(&wh[wv][dig[c]], (unsigned)__popcll(peers));
      old = __shfl(old, ldr, 64);
      wloc[c] = old + before;
    }
    __syncthreads();

    // Phase B: per-digit cross-wave prefix + tile bin starts + advance gbase
    unsigned incl = 0, tot = 0;
    if (tid < 256) {
      const unsigned d = (unsigned)tid;
#pragma unroll
      for (int w = 0; w < 16; ++w) tot += wh[w][d];
      incl = tot;
      for (int off = 1; off < 64; off <<= 1) {
        unsigned t = __shfl_up(incl, off, 64);
        if (lane >= off) incl += t;
      }
      if (lane == 63) wsum[wv] = incl;
    }
    __syncthreads();
    if (tid < 256) {
      const unsigned d = (unsigned)tid;
      unsigned wpre = 0;
      for (int w = 0; w < wv; ++w) wpre += wsum[w];
      const unsigned tstart = incl - tot + wpre;
      const unsigned g = gbase[d];
      gout[d] = g - tstart;
      gbase[d] = g + tot;
      unsigned run = tstart;
#pragma unroll
      for (int w = 0; w < 16; ++w) { const unsigned t = wh[w][d]; wh[w][d] = run; run += t; }
    }
    __syncthreads();

    if (MODE != 2) {
      // Phase C: stage records into LDS in digit order
#pragma unroll
      for (int c = 0; c < 4; ++c) {
        if (val[c]) {
          uint2 r; r.x = cpp[c]; r.y = key[c];
          stg[wh[wv][dig[c]] + wloc[c]] = r;
        }
      }
      __syncthreads();
      // Phase D: coalesced write-out + fused next-pass histogram
      const unsigned nt = min((unsigned)TILE, s1 - t0);
      for (unsigned j = tid; j < nt; j += TPS) {
        const uint2 r = stg[j];
        const unsigned d = (r.y >> shift) & 255u;
        const unsigned pos = gout[d] + j;
        out[pos] = r;
        const unsigned nd = (r.y >> (shift + 8)) & 255u;
        atomicAdd(&h2[nd * NB_S + pos / (unsigned)CH_S], 1u);
      }
    } else {
      // Final pass: rank inline, scatter rank into fillmap[comppos]
#pragma unroll
      for (int c = 0; c < 4; ++c) {
        if (val[c]) {
          const unsigned rank = gout[dig[c]] + wh[wv][dig[c]] + wloc[c];
          fm[cpp[c]] = (rank < (unsigned)KSEL) ? rank : 0xFFFFFFFFu;
        }
      }
    }
    __syncthreads();   // protect wh/gout/gbase before next tile's clear
  }

  if (MODE != 2) {
    unsigned* Hb = Hnext + (size_t)b * 256 * NB_S;
    for (int e = tid; e < 256 * NB_S; e += TPS) {
      unsigned c = h2[e];
      if (c) atomicAdd(&Hb[e], c);
    }
  }
}

// Fused copy+fill: regenerates compaction positions with the SAME traversal as
// k_cscatter, reads fillmap[pos] (sequential), writes out fully coalesced.
__global__ __launch_bounds__(TPB) void k_fill(const uint4* __restrict__ x4,
                                              const unsigned* __restrict__ gb,
                                              const unsigned* __restrict__ fillmap,
                                              const unsigned* __restrict__ ws,
                                              float4* __restrict__ out4) {
  __shared__ unsigned waveTot[4];
  __shared__ unsigned runBase;
  const int b = blockIdx.y, blk = blockIdx.x, tid = threadIdx.x;
  const int lane = tid & 63, wv = tid >> 6;
  const unsigned G = ws[WS_GS + b];
  const unsigned kp = min(ws[WS_KP + b], (unsigned)KCAP);
  if (tid == 0) runBase = ws[WS_COFF + b * NB_C + blk];
  __syncthreads();
  const size_t base4 = ((size_t)b * NPS + (size_t)blk * CH_C) / 4;
  const uint4* g4 = (const uint4*)(gb + (size_t)b * NPS + (size_t)blk * CH_C);
  const unsigned* fm = fillmap + (size_t)b * KCAP;
  const float* mnf = (const float*)(ws + WS_MN);
  const float* mxf = (const float*)(ws + WS_MX);
  const unsigned ebase = (unsigned)blk * (unsigned)CH_C;

  for (int t = 0; t < CH_C / 1024; ++t) {
    const uint4 gv = g4[t * 256 + tid];
    uint4 xv = ((const uint4*)x4)[base4 + t * 256 + tid];
    unsigned k[4] = { gv.x & 0x7FFFFFFFu, gv.y & 0x7FFFFFFFu, gv.z & 0x7FFFFFFFu, gv.w & 0x7FFFFFFFu };
    bool s[4];
    unsigned cnt = 0;
#pragma unroll
    for (int c = 0; c < 4; ++c) { s[c] = (k[c] <= G); cnt += (unsigned)s[c]; }
    unsigned incl = cnt;
    for (int off = 1; off < 64; off <<= 1) {
      unsigned u = __shfl_up(incl, off, 64);
      if (lane >= off) incl += u;
    }
    if (lane == 63) waveTot[wv] = incl;
    __syncthreads();
    const unsigned wt0 = waveTot[0], wt1 = waveTot[1], wt2 = waveTot[2], wt3 = waveTot[3];
    unsigned wpre = 0;
    if (wv > 0) wpre += wt0;
    if (wv > 1) wpre += wt1;
    if (wv > 2) wpre += wt2;
    unsigned pos = runBase + wpre + (incl - cnt);
    unsigned* xw = (unsigned*)&xv;
#pragma unroll
    for (int c = 0; c < 4; ++c) {
      if (s[c]) {
        if (pos < kp) {
          const unsigned r = fm[pos];
          if (r != 0xFFFFFFFFu) {
            const unsigned p = (unsigned)b * (unsigned)KSEL + r;
            unsigned o0, o1;
            threefry2x32(0u, 42u, 0u, p, o0, o1);
            const unsigned bits = o0 ^ o1;
            const float u = __uint_as_float((bits >> 9) | 0x3f800000u) - 1.0f;
            const unsigned e = ebase + (unsigned)t * 1024u + (unsigned)tid * 4u + (unsigned)c;
            const unsigned ch = e >> LOG_HW;
            const float lo = mnf[b * CCH + ch];
            const float hi = mxf[b * CCH + ch];
            xw[c] = __float_as_uint(lo + u * (hi - lo));
          }
        }
        ++pos;
      }
    }
    ((uint4*)out4)[base4 + t * 256 + tid] = xv;
    __syncthreads();
    if (tid == 0) runBase += wt0 + wt1 + wt2 + wt3;
  }
}

extern "C" void kernel_launch(void* const* d_in, const int* in_sizes, int n_in,
                              void* d_out, int out_size, void* d_ws, size_t ws_size,
                              hipStream_t stream) {
  const float* x = (const float*)d_in[0];
  const unsigned* gb = (const unsigned*)d_in[1];   // grad bits
  float* out = (float*)d_out;
  unsigned* ws = (unsigned*)d_ws;
  if (ws_size < WS_NEEDED_BYTES) return;

  unsigned* R1 = ws + WS_FIX_END;                  // keys / records / fillmap
  unsigned* R2 = ws + WS_FIX_END + RECW;           // records
  unsigned* H0 = ws + WS_H0;
  unsigned* H1 = ws + WS_H1;
  unsigned* H2 = ws + WS_H2;
  unsigned* H3 = ws + WS_H3;

  dim3 blk(TPB);
  dim3 sblk(TPS);

  // 0. min/max partials (read-only) ; zero hist region (THA..FIX_END)
  k_mnmx<<<dim3(BN * CCH * SUB), blk, 0, stream>>>((const float4*)x, ws);
  k_mnfin<<<dim3(1), blk, 0, stream>>>(ws);
  {
    const int nz = (int)(WS_FIX_END - WS_THA);
    k_zero<<<dim3((nz + TPB - 1) / TPB), blk, 0, stream>>>(ws + WS_THA, nz);
  }

  // 1. 22-bit prefix threshold via 11+11-bit histogram refinement
  k_thrA<<<dim3(NB_T, BN), blk, 0, stream>>>(gb, ws + WS_THA);
  k_find<<<dim3(BN), blk, 0, stream>>>(ws + WS_THA, ws, 0);
  k_thrB<<<dim3(NB_T, BN), blk, 0, stream>>>(gb, ws + WS_THB, ws);
  k_find<<<dim3(BN), blk, 0, stream>>>(ws + WS_THB, ws, 1);

  // 2. index-ordered compaction (4B keys) + fused pass-1 histogram
  k_ccount<<<dim3(NB_C, BN), blk, 0, stream>>>(gb, ws);
  k_cscan<<<dim3(BN), dim3(64), 0, stream>>>(ws);
  k_cscatter<<<dim3(NB_C, BN), blk, 0, stream>>>(gb, ws, R1, H0);

  // 3. stable LSD radix sort, 4 x 8-bit; final pass scatters ranks into fillmap (R1)
  k_hscan<<<dim3(BN), blk, 0, stream>>>(H0);
  k_sort8<0><<<dim3(NB_S, BN), sblk, 0, stream>>>(R1, (const uint2*)nullptr, (uint2*)R2, nullptr, H0, H1, ws, 0);
  k_hscan<<<dim3(BN), blk, 0, stream>>>(H1);
  k_sort8<1><<<dim3(NB_S, BN), sblk, 0, stream>>>(nullptr, (const uint2*)R2, (uint2*)R1, nullptr, H1, H2, ws, 8);
  k_hscan<<<dim3(BN), blk, 0, stream>>>(H2);
  k_sort8<1><<<dim3(NB_S, BN), sblk, 0, stream>>>(nullptr, (const uint2*)R1, (uint2*)R2, nullptr, H2, H3, ws, 16);
  k_hscan<<<dim3(BN), blk, 0, stream>>>(H3);
  k_sort8<2><<<dim3(NB_S, BN), sblk, 0, stream>>>(nullptr, (const uint2*)R2, (uint2*)nullptr, R1, H3, nullptr, ws, 24);

  // 4. fused copy + fill (sequential reads, coalesced writes)
  k_fill<<<dim3(NB_C, BN), blk, 0, stream>>>((const uint4*)x, gb, R1, ws, (float4*)out);
}

// Round 6
// 779.480 us; speedup vs baseline: 2.9840x; 1.0240x over previous
//
#include <hip/hip_runtime.h>
#include <stdint.h>

#define TPB 256
#define TPS 1024          // threads per sort block

// Problem constants
constexpr int BN   = 64;          // batch
constexpr int CCH  = 3;           // channels
constexpr int HWS  = 262144;      // H*W
constexpr int LOG_HW = 18;
constexpr int NPS  = 786432;      // C*H*W per sample
constexpr int KSEL = 196608;      // K_UPPER
constexpr int KCAP = 200704;      // KSEL + slack for boundary-bin duplicates
constexpr int NB_T = 32;          // blocks/sample for threshold scans
constexpr int CH_T = NPS / NB_T;  // 24576
constexpr int NB_C = 64;          // blocks/sample for compaction/fill scans
constexpr int CH_C = NPS / NB_C;  // 12288
constexpr int WCH  = CH_C / 4;    // 3072 elements per wave subrange
constexpr int NB_S = 8;           // blocks/sample for sort passes
constexpr int CH_S = KCAP / NB_S; // 25088
constexpr int TILE = 4096;        // records per sort tile (TPS * 4)
constexpr int NBINS = 2048;       // threshold-refinement bins
constexpr int SUB  = 8;           // sub-blocks per (b,c) in mnmx

// ws layout (u32 offsets)
constexpr int WS_MN   = 0;        // f32[192]
constexpr int WS_MX   = 192;      // f32[192]
constexpr int WS_V1   = 384;      // u32[64]
constexpr int WS_B1   = 448;      // u32[64]
constexpr int WS_GS   = 512;      // u32[64] inclusive key threshold G*
constexpr int WS_KP   = 576;      // u32[64] compacted count per sample
constexpr int WS_S0   = 640;      // u32[64] selected in ch0
constexpr int WS_S01  = 704;      // u32[64] selected in ch0+ch1
constexpr int WS_CNT  = 768;                      // u32[64][256] per-wave-range counts
constexpr int WS_COFF = WS_CNT + BN * 256;        // 17152
constexpr int WS_MNP  = WS_COFF + BN * 256;       // 33536 ; f32[1536]
constexpr int WS_MXP  = WS_MNP + BN * CCH * SUB;  // 35072 ; f32[1536]
constexpr int WS_CHC  = WS_MXP + BN * CCH * SUB;  // 36608 ; u32[64][3] channel-selected counts
constexpr int WS_THA  = WS_CHC + BN * 4;          // 36864
constexpr int WS_THB  = WS_THA + BN * NBINS;      // 167936
constexpr int WS_H0   = WS_THB + BN * NBINS;      // 299008 ; u32[64][256][NB_S]
constexpr int WS_H1   = WS_H0 + BN * 256 * NB_S;
constexpr int WS_H2   = WS_H1 + BN * 256 * NB_S;
constexpr int WS_H3   = WS_H2 + BN * 256 * NB_S;
constexpr size_t WS_FIX_END = (size_t)WS_H3 + (size_t)BN * 256 * NB_S;  // 823296 words
constexpr size_t RECW = (size_t)BN * KCAP * 2;   // words per uint2 record buffer
constexpr size_t WS_NEEDED_BYTES = (WS_FIX_END + 2 * RECW) * 4;   // 208.8 MB (proven-safe)

// ---------------- threefry2x32 (JAX-exact, partitionable stream) ----------------
__device__ __forceinline__ unsigned rotl32(unsigned x, int r) { return (x << r) | (x >> (32 - r)); }

__device__ __forceinline__ void tf4(unsigned& x0, unsigned& x1, int a, int b, int c, int d) {
  x0 += x1; x1 = rotl32(x1, a); x1 ^= x0;
  x0 += x1; x1 = rotl32(x1, b); x1 ^= x0;
  x0 += x1; x1 = rotl32(x1, c); x1 ^= x0;
  x0 += x1; x1 = rotl32(x1, d); x1 ^= x0;
}

__device__ __forceinline__ void threefry2x32(unsigned k0, unsigned k1, unsigned c0, unsigned c1,
                                             unsigned& o0, unsigned& o1) {
  const unsigned ks2 = k0 ^ k1 ^ 0x1BD11BDAu;
  unsigned x0 = c0 + k0, x1 = c1 + k1;
  tf4(x0, x1, 13, 15, 26, 6);  x0 += k1;  x1 += ks2 + 1u;
  tf4(x0, x1, 17, 29, 16, 24); x0 += ks2; x1 += k0 + 2u;
  tf4(x0, x1, 13, 15, 26, 6);  x0 += k0;  x1 += k1 + 3u;
  tf4(x0, x1, 17, 29, 16, 24); x0 += k1;  x1 += ks2 + 4u;
  tf4(x0, x1, 13, 15, 26, 6);  x0 += ks2; x1 += k0 + 5u;
  o0 = x0; o1 = x1;
}

// ---------------- kernels ----------------
__global__ __launch_bounds__(TPB) void k_zero(unsigned* __restrict__ p, int n) {
  int i = blockIdx.x * TPB + threadIdx.x;
  if (i < n) p[i] = 0u;
}

// per-(b,c) min/max partials (excluding channel's last element) — read-only
__global__ __launch_bounds__(TPB) void k_mnmx(const float4* __restrict__ x,
                                              unsigned* __restrict__ ws) {
  __shared__ float smn[TPB], smx[TPB];
  const int g = blockIdx.x;            // bc*SUB + sub
  const int bc = g / SUB, sub = g - bc * SUB;
  const int Q4 = HWS / 4 / SUB;        // 8192 float4 per sub-block
  const size_t base4 = (size_t)bc * (HWS / 4) + (size_t)sub * Q4;
  const bool last = (sub == SUB - 1);
  const int tid = threadIdx.x;
  float lo = 3.4e38f, hi = -3.4e38f;
  for (int i = tid; i < Q4; i += TPB) {
    float4 v = x[base4 + i];
    if (last && i == Q4 - 1) {         // exclude final element of the channel
      lo = fminf(lo, fminf(fminf(v.x, v.y), v.z));
      hi = fmaxf(hi, fmaxf(fmaxf(v.x, v.y), v.z));
    } else {
      lo = fminf(lo, fminf(fminf(v.x, v.y), fminf(v.z, v.w)));
      hi = fmaxf(hi, fmaxf(fmaxf(v.x, v.y), fmaxf(v.z, v.w)));
    }
  }
  smn[tid] = lo; smx[tid] = hi; __syncthreads();
  for (int s = TPB / 2; s > 0; s >>= 1) {
    if (tid < s) { smn[tid] = fminf(smn[tid], smn[tid + s]); smx[tid] = fmaxf(smx[tid], smx[tid + s]); }
    __syncthreads();
  }
  if (tid == 0) {
    ((float*)(ws + WS_MNP))[g] = smn[0];
    ((float*)(ws + WS_MXP))[g] = smx[0];
  }
}

__global__ __launch_bounds__(TPB) void k_mnfin(unsigned* __restrict__ ws) {
  const int t = threadIdx.x;
  if (t < BN * CCH) {
    const float* mnp = (const float*)(ws + WS_MNP);
    const float* mxp = (const float*)(ws + WS_MXP);
    float lo = 3.4e38f, hi = -3.4e38f;
    for (int s = 0; s < SUB; ++s) {
      lo = fminf(lo, mnp[t * SUB + s]);
      hi = fmaxf(hi, mxp[t * SUB + s]);
    }
    ((float*)(ws + WS_MN))[t] = lo;
    ((float*)(ws + WS_MX))[t] = hi;
  }
}

__global__ __launch_bounds__(TPB) void k_thrA(const unsigned* __restrict__ gb, unsigned* __restrict__ hist) {
  __shared__ unsigned h[NBINS];
  const int b = blockIdx.y, blk = blockIdx.x, tid = threadIdx.x;
  for (int v = tid; v < NBINS; v += TPB) h[v] = 0u;
  __syncthreads();
  const uint4* g4 = (const uint4*)(gb + (size_t)b * NPS + (size_t)blk * CH_T);
  for (int i = tid; i < CH_T / 4; i += TPB) {
    uint4 v = g4[i];
    atomicAdd(&h[(v.x & 0x7FFFFFFFu) >> 21], 1u);
    atomicAdd(&h[(v.y & 0x7FFFFFFFu) >> 21], 1u);
    atomicAdd(&h[(v.z & 0x7FFFFFFFu) >> 21], 1u);
    atomicAdd(&h[(v.w & 0x7FFFFFFFu) >> 21], 1u);
  }
  __syncthreads();
  unsigned* gh = hist + (size_t)b * NBINS;
  for (int v = tid; v < NBINS; v += TPB) if (h[v]) atomicAdd(&gh[v], h[v]);
}

// second refinement round: among elements with top11==V1, histogram mid-11 bits
__global__ __launch_bounds__(TPB) void k_thrB(const unsigned* __restrict__ gb,
                                              unsigned* __restrict__ hist,
                                              const unsigned* __restrict__ ws) {
  __shared__ unsigned h[NBINS];
  const int b = blockIdx.y, blk = blockIdx.x, tid = threadIdx.x;
  for (int v = tid; v < NBINS; v += TPB) h[v] = 0u;
  __syncthreads();
  const unsigned sel = ws[WS_V1 + b];
  const uint4* g4 = (const uint4*)(gb + (size_t)b * NPS + (size_t)blk * CH_T);
  for (int i = tid; i < CH_T / 4; i += TPB) {
    uint4 v = g4[i];
    unsigned a0 = v.x & 0x7FFFFFFFu, a1 = v.y & 0x7FFFFFFFu;
    unsigned a2 = v.z & 0x7FFFFFFFu, a3 = v.w & 0x7FFFFFFFu;
    if ((a0 >> 21) == sel) atomicAdd(&h[(a0 >> 10) & 2047u], 1u);
    if ((a1 >> 21) == sel) atomicAdd(&h[(a1 >> 10) & 2047u], 1u);
    if ((a2 >> 21) == sel) atomicAdd(&h[(a2 >> 10) & 2047u], 1u);
    if ((a3 >> 21) == sel) atomicAdd(&h[(a3 >> 10) & 2047u], 1u);
  }
  __syncthreads();
  unsigned* gh = hist + (size_t)b * NBINS;
  for (int v = tid; v < NBINS; v += TPB) if (h[v]) atomicAdd(&gh[v], h[v]);
}

// mode 0: top 11 bits -> V1, B1 ; mode 1: mid 11 bits -> finalize G* (22-bit prefix), Kp
__global__ __launch_bounds__(TPB) void k_find(const unsigned* __restrict__ hist,
                                              unsigned* __restrict__ ws, int mode) {
  __shared__ unsigned part[TPB];
  const int b = blockIdx.x, tid = threadIdx.x;
  const unsigned* h = hist + (size_t)b * NBINS;
  const int per = NBINS / TPB;
  const unsigned Kt = (mode == 0) ? (unsigned)KSEL : (unsigned)KSEL - ws[WS_B1 + b];
  unsigned vals[8];
  unsigned s = 0;
  for (int j = 0; j < per; ++j) { vals[j] = h[tid * per + j]; s += vals[j]; }
  part[tid] = s; __syncthreads();
  for (int off = 1; off < TPB; off <<= 1) {
    unsigned t = (tid >= off) ? part[tid - off] : 0u;
    __syncthreads(); part[tid] += t; __syncthreads();
  }
  unsigned run = part[tid] - s;
  for (int j = 0; j < per; ++j) {
    const unsigned lo = run, c = vals[j];
    run += c;
    if (lo < Kt && Kt <= run) {
      const unsigned v = (unsigned)(tid * per + j);
      if (mode == 0) {
        ws[WS_V1 + b] = v; ws[WS_B1 + b] = lo;
      } else {
        const unsigned T22 = (ws[WS_V1 + b] << 11) | v;
        ws[WS_GS + b] = (T22 << 10) | 1023u;        // inclusive 31-bit threshold
        unsigned kp = ws[WS_B1 + b] + lo + c;       // countLess(T22) + countEq(T22)
        if (kp > (unsigned)KCAP) kp = (unsigned)KCAP;
        ws[WS_KP + b] = kp;
      }
    }
  }
}

// per-wave-range selected counts + per-channel totals
__global__ __launch_bounds__(TPB) void k_ccount(const unsigned* __restrict__ gb, unsigned* __restrict__ ws) {
  __shared__ unsigned chs[3];
  const int b = blockIdx.y, blk = blockIdx.x, tid = threadIdx.x;
  const int lane = tid & 63, wv = tid >> 6;
  if (tid < 3) chs[tid] = 0u;
  __syncthreads();
  const unsigned G = ws[WS_GS + b];
  const uint4* g4 = (const uint4*)(gb + (size_t)b * NPS + (size_t)blk * CH_C) + wv * (WCH / 4);
  const unsigned e0 = (unsigned)blk * CH_C + (unsigned)wv * WCH;
  unsigned cnt = 0, cc0 = 0, cc1 = 0, cc2 = 0;
  for (int it = 0; it < WCH / 256; ++it) {
    const uint4 v = g4[it * 64 + lane];
    const unsigned e = e0 + (unsigned)it * 256u + (unsigned)lane * 4u;
    const unsigned k[4] = { v.x & 0x7FFFFFFFu, v.y & 0x7FFFFFFFu, v.z & 0x7FFFFFFFu, v.w & 0x7FFFFFFFu };
#pragma unroll
    for (int c = 0; c < 4; ++c) {
      if (k[c] <= G) {
        ++cnt;
        const unsigned ch = (e + (unsigned)c) >> LOG_HW;
        if (ch == 0) ++cc0; else if (ch == 1) ++cc1; else ++cc2;
      }
    }
  }
  for (int off = 32; off >= 1; off >>= 1) cnt += __shfl_down(cnt, off, 64);
  if (lane == 0) ws[WS_CNT + b * 256 + blk * 4 + wv] = cnt;
  if (cc0) atomicAdd(&chs[0], cc0);
  if (cc1) atomicAdd(&chs[1], cc1);
  if (cc2) atomicAdd(&chs[2], cc2);
  __syncthreads();
  if (tid < 3 && chs[tid]) atomicAdd(&ws[WS_CHC + b * 4 + tid], chs[tid]);
}

// scan 256 per-wave-range counts per sample -> COFF ; channel boundaries S0/S01
__global__ __launch_bounds__(TPB) void k_cscan(unsigned* __restrict__ ws) {
  __shared__ unsigned wsum[4];
  const int b = blockIdx.x, tid = threadIdx.x;
  const int lane = tid & 63, wv = tid >> 6;
  const unsigned cnt = ws[WS_CNT + b * 256 + tid];
  unsigned incl = cnt;
  for (int off = 1; off < 64; off <<= 1) {
    unsigned t = __shfl_up(incl, off, 64);
    if (lane >= off) incl += t;
  }
  if (lane == 63) wsum[wv] = incl;
  __syncthreads();
  unsigned wpre = 0;
  for (int w = 0; w < wv; ++w) wpre += wsum[w];
  ws[WS_COFF + b * 256 + tid] = incl - cnt + wpre;
  if (tid == 0) {
    const unsigned s0 = ws[WS_CHC + b * 4 + 0];
    ws[WS_S0 + b] = s0;
    ws[WS_S01 + b] = s0 + ws[WS_CHC + b * 4 + 1];
  }
}

// Index-ordered compaction (wave-independent, no barriers in loop) -> 4B keys,
// fused pass-1 per-destblock digit histogram into H0.
__global__ __launch_bounds__(TPB) void k_cscatter(const unsigned* __restrict__ gb,
                                                  const unsigned* __restrict__ ws,
                                                  unsigned* __restrict__ keyArr,
                                                  unsigned* __restrict__ H0) {
  __shared__ unsigned h2[256 * NB_S];   // 8 KB
  const int b = blockIdx.y, blk = blockIdx.x, tid = threadIdx.x;
  const int lane = tid & 63, wv = tid >> 6;
  for (int e = tid; e < 256 * NB_S; e += TPB) h2[e] = 0u;
  __syncthreads();
  const unsigned G = ws[WS_GS + b];
  unsigned base = ws[WS_COFF + b * 256 + blk * 4 + wv];
  const uint4* g4 = (const uint4*)(gb + (size_t)b * NPS + (size_t)blk * CH_C) + wv * (WCH / 4);
  unsigned* ka = keyArr + (size_t)b * KCAP;
  for (int it = 0; it < WCH / 256; ++it) {
    const uint4 v = g4[it * 64 + lane];
    unsigned k[4] = { v.x & 0x7FFFFFFFu, v.y & 0x7FFFFFFFu, v.z & 0x7FFFFFFFu, v.w & 0x7FFFFFFFu };
    bool s[4];
    unsigned cnt = 0;
#pragma unroll
    for (int c = 0; c < 4; ++c) { s[c] = (k[c] <= G); cnt += (unsigned)s[c]; }
    unsigned incl = cnt;
    for (int off = 1; off < 64; off <<= 1) {
      unsigned u = __shfl_up(incl, off, 64);
      if (lane >= off) incl += u;
    }
    const unsigned wtot = __shfl(incl, 63, 64);
    unsigned pos = base + incl - cnt;
#pragma unroll
    for (int c = 0; c < 4; ++c) {
      if (s[c]) {
        if (pos < (unsigned)KCAP) {
          ka[pos] = k[c];
          atomicAdd(&h2[(k[c] & 255u) * NB_S + pos / (unsigned)CH_S], 1u);
        }
        ++pos;
      }
    }
    base += wtot;
  }
  __syncthreads();
  unsigned* Hb = H0 + (size_t)b * 256 * NB_S;
  for (int e = tid; e < 256 * NB_S; e += TPB) {
    unsigned c = h2[e];
    if (c) atomicAdd(&Hb[e], c);
  }
}

// per-sample scan of H[b][256][NB_S] counts -> global output bases (lexicographic dig,blk)
__global__ __launch_bounds__(TPB) void k_hscan(unsigned* __restrict__ H) {
  __shared__ unsigned wsum[4];
  const int b = blockIdx.x, tid = threadIdx.x;
  const int lane = tid & 63, wv = tid >> 6;
  unsigned* Hb = H + (size_t)b * 256 * NB_S;
  unsigned row[NB_S];
  unsigned run = 0;
#pragma unroll
  for (int k = 0; k < NB_S; ++k) {
    unsigned t = Hb[tid * NB_S + k];
    row[k] = run; run += t;
  }
  unsigned incl = run;
  for (int off = 1; off < 64; off <<= 1) {
    unsigned t = __shfl_up(incl, off, 64);
    if (lane >= off) incl += t;
  }
  if (lane == 63) wsum[wv] = incl;
  __syncthreads();
  unsigned wpre = 0;
  for (int w = 0; w < wv; ++w) wpre += wsum[w];
  const unsigned excl = incl - run + wpre;
#pragma unroll
  for (int k = 0; k < NB_S; ++k) Hb[tid * NB_S + k] = row[k] + excl;
}

// One stable 8-bit LSD radix pass, TPS=1024 threads, tile=4096 records.
// MODE 0: input = 4B key array (comppos == position) -> records + next hist.
// MODE 1: records -> records + next hist (LDS-staged coalesced output).
// MODE 2: final: rank inline -> threefry fill VALUE into fillmap[comppos] (~0u if rank>=KSEL).
template<int MODE>
__global__ __launch_bounds__(TPS) void k_sort8(const unsigned* __restrict__ keyIn,
                                               const uint2* __restrict__ inR,
                                               uint2* __restrict__ outR,
                                               unsigned* __restrict__ fillmap,
                                               const unsigned* __restrict__ Hcur,
                                               unsigned* __restrict__ Hnext,
                                               const unsigned* __restrict__ ws,
                                               int shift) {
  __shared__ unsigned wh[16][256];       // per-wave digit counts -> per-wave in-tile bases
  __shared__ unsigned gout[256];         // gbase[d] - tstart[d] (tile-local -> global)
  __shared__ unsigned gbase[256];        // running global base per digit
  __shared__ unsigned wsum[4];
  __shared__ uint2    stg[(MODE == 2) ? 1 : TILE];
  __shared__ unsigned h2[(MODE == 2) ? 1 : 256 * NB_S];
  const int b = blockIdx.y, blk = blockIdx.x, tid = threadIdx.x;
  const int lane = tid & 63, wv = tid >> 6;
  const unsigned long long ltm = (1ull << lane) - 1ull;
  const unsigned kp = min(ws[WS_KP + b], (unsigned)KCAP);
  const unsigned s0 = (unsigned)blk * CH_S;
  const unsigned s1 = min(s0 + (unsigned)CH_S, kp);
  const unsigned* ki = keyIn + (size_t)b * KCAP;
  const uint2* in = inR + (size_t)b * KCAP;
  uint2* out = outR + (size_t)b * KCAP;
  unsigned* fm = fillmap + (size_t)b * KCAP;

  // MODE 2 per-sample uniforms
  unsigned S0 = 0, S01 = 0;
  float l0 = 0, l1 = 0, l2 = 0, h0 = 0, h1 = 0, h2v = 0;
  if (MODE == 2) {
    S0 = ws[WS_S0 + b]; S01 = ws[WS_S01 + b];
    const float* mnf = (const float*)(ws + WS_MN);
    const float* mxf = (const float*)(ws + WS_MX);
    l0 = mnf[b * CCH]; l1 = mnf[b * CCH + 1]; l2 = mnf[b * CCH + 2];
    h0 = mxf[b * CCH]; h1 = mxf[b * CCH + 1]; h2v = mxf[b * CCH + 2];
  }

  for (int d = tid; d < 256; d += TPS) gbase[d] = Hcur[((size_t)b * 256 + d) * NB_S + blk];
  if (MODE != 2) for (int e = tid; e < 256 * NB_S; e += TPS) h2[e] = 0u;
  __syncthreads();

  for (unsigned t0 = s0; t0 < s1; t0 += (unsigned)TILE) {
    { uint4* w4 = (uint4*)&wh[0][0];
      w4[tid] = make_uint4(0u, 0u, 0u, 0u); }
    __syncthreads();

    // Phase A: rank within wave (order: wv, chunk, lane == memory order)
    unsigned key[4], cpp[4], wloc[4], dig[4];
    bool val[4];
    const unsigned wbase = t0 + (unsigned)wv * 256u;
#pragma unroll
    for (int c = 0; c < 4; ++c) {
      const unsigned i = wbase + (unsigned)c * 64u + (unsigned)lane;
      val[c] = (i < s1);
      if (MODE == 0) { cpp[c] = i; key[c] = val[c] ? ki[i] : 0u; }
      else { uint2 r = val[c] ? in[i] : make_uint2(0u, 0u); cpp[c] = r.x; key[c] = r.y; }
      dig[c] = (key[c] >> shift) & 255u;
      unsigned long long peers = __ballot(val[c]);
#pragma unroll
      for (int bit = 0; bit < 8; ++bit) {
        unsigned long long bb = __ballot(val[c] && ((dig[c] >> bit) & 1u));
        peers &= ((dig[c] >> bit) & 1u) ? bb : ~bb;
      }
      const unsigned before = (unsigned)__popcll(peers & ltm);
      int ldr = __ffsll((unsigned long long)peers) - 1;
      if (ldr < 0) ldr = 0;
      unsigned old = 0;
      if (val[c] && lane == ldr) old = atomicAdd(&wh[wv][dig[c]], (unsigned)__popcll(peers));
      old = __shfl(old, ldr, 64);
      wloc[c] = old + before;
    }
    __syncthreads();

    // Phase B: per-digit cross-wave prefix + tile bin starts + advance gbase
    unsigned incl = 0, tot = 0;
    if (tid < 256) {
      const unsigned d = (unsigned)tid;
#pragma unroll
      for (int w = 0; w < 16; ++w) tot += wh[w][d];
      incl = tot;
      for (int off = 1; off < 64; off <<= 1) {
        unsigned t = __shfl_up(incl, off, 64);
        if (lane >= off) incl += t;
      }
      if (lane == 63) wsum[wv] = incl;
    }
    __syncthreads();
    if (tid < 256) {
      const unsigned d = (unsigned)tid;
      unsigned wpre = 0;
      for (int w = 0; w < wv; ++w) wpre += wsum[w];
      const unsigned tstart = incl - tot + wpre;
      const unsigned g = gbase[d];
      gout[d] = g - tstart;
      gbase[d] = g + tot;
      unsigned run = tstart;
#pragma unroll
      for (int w = 0; w < 16; ++w) { const unsigned t = wh[w][d]; wh[w][d] = run; run += t; }
    }
    __syncthreads();

    if (MODE != 2) {
      // Phase C: stage records into LDS in digit order
#pragma unroll
      for (int c = 0; c < 4; ++c) {
        if (val[c]) {
          uint2 r; r.x = cpp[c]; r.y = key[c];
          stg[wh[wv][dig[c]] + wloc[c]] = r;
        }
      }
      __syncthreads();
      // Phase D: coalesced write-out + fused next-pass histogram
      const unsigned nt = min((unsigned)TILE, s1 - t0);
      for (unsigned j = tid; j < nt; j += TPS) {
        const uint2 r = stg[j];
        const unsigned d = (r.y >> shift) & 255u;
        const unsigned pos = gout[d] + j;
        out[pos] = r;
        const unsigned nd = (r.y >> (shift + 8)) & 255u;
        atomicAdd(&h2[nd * NB_S + pos / (unsigned)CH_S], 1u);
      }
    } else {
      // Final pass: rank inline -> fill VALUE into fillmap[comppos]
#pragma unroll
      for (int c = 0; c < 4; ++c) {
        if (val[c]) {
          const unsigned rank = gout[dig[c]] + wh[wv][dig[c]] + wloc[c];
          unsigned res = 0xFFFFFFFFu;
          if (rank < (unsigned)KSEL) {
            const unsigned p = (unsigned)b * (unsigned)KSEL + rank;
            unsigned o0, o1;
            threefry2x32(0u, 42u, 0u, p, o0, o1);
            const unsigned bits = o0 ^ o1;
            const float u = __uint_as_float((bits >> 9) | 0x3f800000u) - 1.0f;
            const unsigned ch = (unsigned)(cpp[c] >= S0) + (unsigned)(cpp[c] >= S01);
            const float lo = (ch == 0) ? l0 : ((ch == 1) ? l1 : l2);
            const float hi = (ch == 0) ? h0 : ((ch == 1) ? h1 : h2v);
            res = __float_as_uint(lo + u * (hi - lo));
          }
          fm[cpp[c]] = res;
        }
      }
    }
    __syncthreads();   // protect wh/gout/gbase before next tile's clear
  }

  if (MODE != 2) {
    unsigned* Hb = Hnext + (size_t)b * 256 * NB_S;
    for (int e = tid; e < 256 * NB_S; e += TPS) {
      unsigned c = h2[e];
      if (c) atomicAdd(&Hb[e], c);
    }
  }
}

// Fused copy+fill: regenerates compaction positions with the SAME wave-independent
// traversal as k_cscatter; reads fill VALUES from fillmap; coalesced out writes.
__global__ __launch_bounds__(TPB) void k_fill(const uint4* __restrict__ x4,
                                              const unsigned* __restrict__ gb,
                                              const unsigned* __restrict__ fillmap,
                                              const unsigned* __restrict__ ws,
                                              uint4* __restrict__ out4) {
  const int b = blockIdx.y, blk = blockIdx.x, tid = threadIdx.x;
  const int lane = tid & 63, wv = tid >> 6;
  const unsigned G = ws[WS_GS + b];
  const unsigned kp = min(ws[WS_KP + b], (unsigned)KCAP);
  unsigned base = ws[WS_COFF + b * 256 + blk * 4 + wv];
  const size_t t4 = (size_t)b * (NPS / 4) + (size_t)blk * (CH_C / 4) + (size_t)wv * (WCH / 4);
  const unsigned* fm = fillmap + (size_t)b * KCAP;
  for (int it = 0; it < WCH / 256; ++it) {
    const size_t a = t4 + it * 64 + lane;
    const uint4 gv = ((const uint4*)gb)[a];
    uint4 xv = x4[a];
    unsigned k[4] = { gv.x & 0x7FFFFFFFu, gv.y & 0x7FFFFFFFu, gv.z & 0x7FFFFFFFu, gv.w & 0x7FFFFFFFu };
    bool s[4];
    unsigned cnt = 0;
#pragma unroll
    for (int c = 0; c < 4; ++c) { s[c] = (k[c] <= G); cnt += (unsigned)s[c]; }
    unsigned incl = cnt;
    for (int off = 1; off < 64; off <<= 1) {
      unsigned u = __shfl_up(incl, off, 64);
      if (lane >= off) incl += u;
    }
    const unsigned wtot = __shfl(incl, 63, 64);
    unsigned pos = base + incl - cnt;
    unsigned* xw = (unsigned*)&xv;
#pragma unroll
    for (int c = 0; c < 4; ++c) {
      if (s[c]) {
        if (pos < kp) {
          const unsigned r = fm[pos];
          if (r != 0xFFFFFFFFu) xw[c] = r;
        }
        ++pos;
      }
    }
    out4[a] = xv;
    base += wtot;
  }
}

extern "C" void kernel_launch(void* const* d_in, const int* in_sizes, int n_in,
                              void* d_out, int out_size, void* d_ws, size_t ws_size,
                              hipStream_t stream) {
  const float* x = (const float*)d_in[0];
  const unsigned* gb = (const unsigned*)d_in[1];   // grad bits
  float* out = (float*)d_out;
  unsigned* ws = (unsigned*)d_ws;
  if (ws_size < WS_NEEDED_BYTES) return;

  unsigned* R1 = ws + WS_FIX_END;                  // keys / records / fillmap
  unsigned* R2 = ws + WS_FIX_END + RECW;           // records
  unsigned* H0 = ws + WS_H0;
  unsigned* H1 = ws + WS_H1;
  unsigned* H2 = ws + WS_H2;
  unsigned* H3 = ws + WS_H3;

  dim3 blk(TPB);
  dim3 sblk(TPS);

  // 0. min/max partials (read-only) ; zero chCnt + hist region
  k_mnmx<<<dim3(BN * CCH * SUB), blk, 0, stream>>>((const float4*)x, ws);
  k_mnfin<<<dim3(1), blk, 0, stream>>>(ws);
  {
    const int nz = (int)(WS_FIX_END - WS_CHC);
    k_zero<<<dim3((nz + TPB - 1) / TPB), blk, 0, stream>>>(ws + WS_CHC, nz);
  }

  // 1. 22-bit prefix threshold via 11+11-bit histogram refinement
  k_thrA<<<dim3(NB_T, BN), blk, 0, stream>>>(gb, ws + WS_THA);
  k_find<<<dim3(BN), blk, 0, stream>>>(ws + WS_THA, ws, 0);
  k_thrB<<<dim3(NB_T, BN), blk, 0, stream>>>(gb, ws + WS_THB, ws);
  k_find<<<dim3(BN), blk, 0, stream>>>(ws + WS_THB, ws, 1);

  // 2. per-wave-range counts + channel totals ; scan ; compaction + pass-1 hist
  k_ccount<<<dim3(NB_C, BN), blk, 0, stream>>>(gb, ws);
  k_cscan<<<dim3(BN), blk, 0, stream>>>(ws);
  k_cscatter<<<dim3(NB_C, BN), blk, 0, stream>>>(gb, ws, R1, H0);

  // 3. stable LSD radix sort, 4 x 8-bit; final pass writes fill VALUES into fillmap (R1)
  k_hscan<<<dim3(BN), blk, 0, stream>>>(H0);
  k_sort8<0><<<dim3(NB_S, BN), sblk, 0, stream>>>(R1, (const uint2*)nullptr, (uint2*)R2, nullptr, H0, H1, ws, 0);
  k_hscan<<<dim3(BN), blk, 0, stream>>>(H1);
  k_sort8<1><<<dim3(NB_S, BN), sblk, 0, stream>>>(nullptr, (const uint2*)R2, (uint2*)R1, nullptr, H1, H2, ws, 8);
  k_hscan<<<dim3(BN), blk, 0, stream>>>(H2);
  k_sort8<1><<<dim3(NB_S, BN), sblk, 0, stream>>>(nullptr, (const uint2*)R1, (uint2*)R2, nullptr, H2, H3, ws, 16);
  k_hscan<<<dim3(BN), blk, 0, stream>>>(H3);
  k_sort8<2><<<dim3(NB_S, BN), sblk, 0, stream>>>(nullptr, (const uint2*)R2, (uint2*)nullptr, R1, H3, nullptr, ws, 24);

  // 4. fused copy + fill (pure streaming, no threefry, no barriers)
  k_fill<<<dim3(NB_C, BN), blk, 0, stream>>>((const uint4*)x, gb, R1, ws, (uint4*)out);
}

// Round 8
// 768.635 us; speedup vs baseline: 3.0261x; 1.0141x over previous
//
#include <hip/hip_runtime.h>
#include <stdint.h>

#define TPB 256
#define TPS 1024          // threads per sort block

// Problem constants
constexpr int BN   = 64;          // batch
constexpr int CCH  = 3;           // channels
constexpr int HWS  = 262144;      // H*W
constexpr int LOG_HW = 18;
constexpr int NPS  = 786432;      // C*H*W per sample
constexpr int KSEL = 196608;      // K_UPPER
constexpr int KCAP = 200704;      // KSEL + slack for boundary-bin duplicates
constexpr int NB_T = 32;          // blocks/sample for threshold scans
constexpr int CH_T = NPS / NB_T;  // 24576
constexpr int NB_C = 64;          // blocks/sample for compaction/fill scans
constexpr int CH_C = NPS / NB_C;  // 12288
constexpr int WCH  = CH_C / 4;    // 3072 elements per wave subrange
constexpr int NB_S = 8;           // blocks/sample for sort passes
constexpr int CH_S = KCAP / NB_S; // 25088
constexpr int TILE = 4096;        // records per sort tile (TPS * 4)
constexpr int NBINS = 2048;       // threshold-refinement bins
constexpr int SUB  = 8;           // sub-blocks per (b,c) in mnmx

// native vector type for nontemporal builtins (HIP uint4 is a class type)
typedef unsigned u32x4 __attribute__((ext_vector_type(4)));

// ws layout (u32 offsets)
constexpr int WS_MN   = 0;        // f32[192]
constexpr int WS_MX   = 192;      // f32[192]
constexpr int WS_V1   = 384;      // u32[64]
constexpr int WS_B1   = 448;      // u32[64]
constexpr int WS_GS   = 512;      // u32[64] inclusive key threshold G*
constexpr int WS_KP   = 576;      // u32[64] compacted count per sample
constexpr int WS_S0   = 640;      // u32[64] selected in ch0
constexpr int WS_S01  = 704;      // u32[64] selected in ch0+ch1
constexpr int WS_CNT  = 768;                      // u32[64][256] per-wave-range counts
constexpr int WS_COFF = WS_CNT + BN * 256;        // 17152
constexpr int WS_MNP  = WS_COFF + BN * 256;       // 33536 ; f32[1536]
constexpr int WS_MXP  = WS_MNP + BN * CCH * SUB;  // 35072 ; f32[1536]
constexpr int WS_CHC  = WS_MXP + BN * CCH * SUB;  // 36608 ; u32[64][3] channel-selected counts
constexpr int WS_THA  = WS_CHC + BN * 4;          // 36864
constexpr int WS_THB  = WS_THA + BN * NBINS;      // 167936
constexpr int WS_H0   = WS_THB + BN * NBINS;      // 299008 ; u32[64][256][NB_S]
constexpr int WS_H1   = WS_H0 + BN * 256 * NB_S;
constexpr int WS_H2   = WS_H1 + BN * 256 * NB_S;
constexpr int WS_H3   = WS_H2 + BN * 256 * NB_S;
constexpr size_t WS_FIX_END = (size_t)WS_H3 + (size_t)BN * 256 * NB_S;  // 823296 words
constexpr size_t RECW = (size_t)BN * KCAP * 2;   // words per uint2 record buffer
constexpr size_t WS_NEEDED_BYTES = (WS_FIX_END + 2 * RECW) * 4;   // 208.8 MB (proven-safe)

// ---------------- threefry2x32 (JAX-exact, partitionable stream) ----------------
__device__ __forceinline__ unsigned rotl32(unsigned x, int r) { return (x << r) | (x >> (32 - r)); }

__device__ __forceinline__ void tf4(unsigned& x0, unsigned& x1, int a, int b, int c, int d) {
  x0 += x1; x1 = rotl32(x1, a); x1 ^= x0;
  x0 += x1; x1 = rotl32(x1, b); x1 ^= x0;
  x0 += x1; x1 = rotl32(x1, c); x1 ^= x0;
  x0 += x1; x1 = rotl32(x1, d); x1 ^= x0;
}

__device__ __forceinline__ void threefry2x32(unsigned k0, unsigned k1, unsigned c0, unsigned c1,
                                             unsigned& o0, unsigned& o1) {
  const unsigned ks2 = k0 ^ k1 ^ 0x1BD11BDAu;
  unsigned x0 = c0 + k0, x1 = c1 + k1;
  tf4(x0, x1, 13, 15, 26, 6);  x0 += k1;  x1 += ks2 + 1u;
  tf4(x0, x1, 17, 29, 16, 24); x0 += ks2; x1 += k0 + 2u;
  tf4(x0, x1, 13, 15, 26, 6);  x0 += k0;  x1 += k1 + 3u;
  tf4(x0, x1, 17, 29, 16, 24); x0 += k1;  x1 += ks2 + 4u;
  tf4(x0, x1, 13, 15, 26, 6);  x0 += ks2; x1 += k0 + 5u;
  o0 = x0; o1 = x1;
}

// ---------------- kernels ----------------
__global__ __launch_bounds__(TPB) void k_zero(unsigned* __restrict__ p, int n) {
  int i = blockIdx.x * TPB + threadIdx.x;
  if (i < n) p[i] = 0u;
}

// per-(b,c) min/max partials (excluding channel's last element) — read-only
__global__ __launch_bounds__(TPB) void k_mnmx(const float4* __restrict__ x,
                                              unsigned* __restrict__ ws) {
  __shared__ float smn[TPB], smx[TPB];
  const int g = blockIdx.x;            // bc*SUB + sub
  const int bc = g / SUB, sub = g - bc * SUB;
  const int Q4 = HWS / 4 / SUB;        // 8192 float4 per sub-block
  const size_t base4 = (size_t)bc * (HWS / 4) + (size_t)sub * Q4;
  const bool last = (sub == SUB - 1);
  const int tid = threadIdx.x;
  float lo = 3.4e38f, hi = -3.4e38f;
  for (int i = tid; i < Q4; i += TPB) {
    float4 v = x[base4 + i];
    if (last && i == Q4 - 1) {         // exclude final element of the channel
      lo = fminf(lo, fminf(fminf(v.x, v.y), v.z));
      hi = fmaxf(hi, fmaxf(fmaxf(v.x, v.y), v.z));
    } else {
      lo = fminf(lo, fminf(fminf(v.x, v.y), fminf(v.z, v.w)));
      hi = fmaxf(hi, fmaxf(fmaxf(v.x, v.y), fmaxf(v.z, v.w)));
    }
  }
  smn[tid] = lo; smx[tid] = hi; __syncthreads();
  for (int s = TPB / 2; s > 0; s >>= 1) {
    if (tid < s) { smn[tid] = fminf(smn[tid], smn[tid + s]); smx[tid] = fmaxf(smx[tid], smx[tid + s]); }
    __syncthreads();
  }
  if (tid == 0) {
    ((float*)(ws + WS_MNP))[g] = smn[0];
    ((float*)(ws + WS_MXP))[g] = smx[0];
  }
}

__global__ __launch_bounds__(TPB) void k_mnfin(unsigned* __restrict__ ws) {
  const int t = threadIdx.x;
  if (t < BN * CCH) {
    const float* mnp = (const float*)(ws + WS_MNP);
    const float* mxp = (const float*)(ws + WS_MXP);
    float lo = 3.4e38f, hi = -3.4e38f;
    for (int s = 0; s < SUB; ++s) {
      lo = fminf(lo, mnp[t * SUB + s]);
      hi = fmaxf(hi, mxp[t * SUB + s]);
    }
    ((float*)(ws + WS_MN))[t] = lo;
    ((float*)(ws + WS_MX))[t] = hi;
  }
}

__global__ __launch_bounds__(TPB) void k_thrA(const unsigned* __restrict__ gb, unsigned* __restrict__ hist) {
  __shared__ unsigned h[NBINS];
  const int b = blockIdx.y, blk = blockIdx.x, tid = threadIdx.x;
  for (int v = tid; v < NBINS; v += TPB) h[v] = 0u;
  __syncthreads();
  const uint4* g4 = (const uint4*)(gb + (size_t)b * NPS + (size_t)blk * CH_T);
  for (int i = tid; i < CH_T / 4; i += TPB) {
    uint4 v = g4[i];
    atomicAdd(&h[(v.x & 0x7FFFFFFFu) >> 21], 1u);
    atomicAdd(&h[(v.y & 0x7FFFFFFFu) >> 21], 1u);
    atomicAdd(&h[(v.z & 0x7FFFFFFFu) >> 21], 1u);
    atomicAdd(&h[(v.w & 0x7FFFFFFFu) >> 21], 1u);
  }
  __syncthreads();
  unsigned* gh = hist + (size_t)b * NBINS;
  for (int v = tid; v < NBINS; v += TPB) if (h[v]) atomicAdd(&gh[v], h[v]);
}

// second refinement round: among elements with top11==V1, histogram mid-11 bits
__global__ __launch_bounds__(TPB) void k_thrB(const unsigned* __restrict__ gb,
                                              unsigned* __restrict__ hist,
                                              const unsigned* __restrict__ ws) {
  __shared__ unsigned h[NBINS];
  const int b = blockIdx.y, blk = blockIdx.x, tid = threadIdx.x;
  for (int v = tid; v < NBINS; v += TPB) h[v] = 0u;
  __syncthreads();
  const unsigned sel = ws[WS_V1 + b];
  const uint4* g4 = (const uint4*)(gb + (size_t)b * NPS + (size_t)blk * CH_T);
  for (int i = tid; i < CH_T / 4; i += TPB) {
    uint4 v = g4[i];
    unsigned a0 = v.x & 0x7FFFFFFFu, a1 = v.y & 0x7FFFFFFFu;
    unsigned a2 = v.z & 0x7FFFFFFFu, a3 = v.w & 0x7FFFFFFFu;
    if ((a0 >> 21) == sel) atomicAdd(&h[(a0 >> 10) & 2047u], 1u);
    if ((a1 >> 21) == sel) atomicAdd(&h[(a1 >> 10) & 2047u], 1u);
    if ((a2 >> 21) == sel) atomicAdd(&h[(a2 >> 10) & 2047u], 1u);
    if ((a3 >> 21) == sel) atomicAdd(&h[(a3 >> 10) & 2047u], 1u);
  }
  __syncthreads();
  unsigned* gh = hist + (size_t)b * NBINS;
  for (int v = tid; v < NBINS; v += TPB) if (h[v]) atomicAdd(&gh[v], h[v]);
}

// mode 0: top 11 bits -> V1, B1 ; mode 1: mid 11 bits -> finalize G* (22-bit prefix), Kp
__global__ __launch_bounds__(TPB) void k_find(const unsigned* __restrict__ hist,
                                              unsigned* __restrict__ ws, int mode) {
  __shared__ unsigned part[TPB];
  const int b = blockIdx.x, tid = threadIdx.x;
  const unsigned* h = hist + (size_t)b * NBINS;
  const int per = NBINS / TPB;
  const unsigned Kt = (mode == 0) ? (unsigned)KSEL : (unsigned)KSEL - ws[WS_B1 + b];
  unsigned vals[8];
  unsigned s = 0;
  for (int j = 0; j < per; ++j) { vals[j] = h[tid * per + j]; s += vals[j]; }
  part[tid] = s; __syncthreads();
  for (int off = 1; off < TPB; off <<= 1) {
    unsigned t = (tid >= off) ? part[tid - off] : 0u;
    __syncthreads(); part[tid] += t; __syncthreads();
  }
  unsigned run = part[tid] - s;
  for (int j = 0; j < per; ++j) {
    const unsigned lo = run, c = vals[j];
    run += c;
    if (lo < Kt && Kt <= run) {
      const unsigned v = (unsigned)(tid * per + j);
      if (mode == 0) {
        ws[WS_V1 + b] = v; ws[WS_B1 + b] = lo;
      } else {
        const unsigned T22 = (ws[WS_V1 + b] << 11) | v;
        ws[WS_GS + b] = (T22 << 10) | 1023u;        // inclusive 31-bit threshold
        unsigned kp = ws[WS_B1 + b] + lo + c;       // countLess(T22) + countEq(T22)
        if (kp > (unsigned)KCAP) kp = (unsigned)KCAP;
        ws[WS_KP + b] = kp;
      }
    }
  }
}

// per-wave-range selected counts + per-channel totals  (1-D XCD-grouped grid)
__global__ __launch_bounds__(TPB) void k_ccount(const unsigned* __restrict__ gb, unsigned* __restrict__ ws) {
  __shared__ unsigned chs[3];
  const int bid = blockIdx.x;
  const int b = bid & 63, blk = bid >> 6, tid = threadIdx.x;
  const int lane = tid & 63, wv = tid >> 6;
  if (tid < 3) chs[tid] = 0u;
  __syncthreads();
  const unsigned G = ws[WS_GS + b];
  const uint4* g4 = (const uint4*)(gb + (size_t)b * NPS + (size_t)blk * CH_C) + wv * (WCH / 4);
  const unsigned e0 = (unsigned)blk * CH_C + (unsigned)wv * WCH;
  unsigned cnt = 0, cc0 = 0, cc1 = 0, cc2 = 0;
  for (int it = 0; it < WCH / 256; ++it) {
    const uint4 v = g4[it * 64 + lane];
    const unsigned e = e0 + (unsigned)it * 256u + (unsigned)lane * 4u;
    const unsigned k[4] = { v.x & 0x7FFFFFFFu, v.y & 0x7FFFFFFFu, v.z & 0x7FFFFFFFu, v.w & 0x7FFFFFFFu };
#pragma unroll
    for (int c = 0; c < 4; ++c) {
      if (k[c] <= G) {
        ++cnt;
        const unsigned ch = (e + (unsigned)c) >> LOG_HW;
        if (ch == 0) ++cc0; else if (ch == 1) ++cc1; else ++cc2;
      }
    }
  }
  for (int off = 32; off >= 1; off >>= 1) cnt += __shfl_down(cnt, off, 64);
  if (lane == 0) ws[WS_CNT + b * 256 + blk * 4 + wv] = cnt;
  if (cc0) atomicAdd(&chs[0], cc0);
  if (cc1) atomicAdd(&chs[1], cc1);
  if (cc2) atomicAdd(&chs[2], cc2);
  __syncthreads();
  if (tid < 3 && chs[tid]) atomicAdd(&ws[WS_CHC + b * 4 + tid], chs[tid]);
}

// scan 256 per-wave-range counts per sample -> COFF ; channel boundaries S0/S01
__global__ __launch_bounds__(TPB) void k_cscan(unsigned* __restrict__ ws) {
  __shared__ unsigned wsum[4];
  const int b = blockIdx.x, tid = threadIdx.x;
  const int lane = tid & 63, wv = tid >> 6;
  const unsigned cnt = ws[WS_CNT + b * 256 + tid];
  unsigned incl = cnt;
  for (int off = 1; off < 64; off <<= 1) {
    unsigned t = __shfl_up(incl, off, 64);
    if (lane >= off) incl += t;
  }
  if (lane == 63) wsum[wv] = incl;
  __syncthreads();
  unsigned wpre = 0;
  for (int w = 0; w < wv; ++w) wpre += wsum[w];
  ws[WS_COFF + b * 256 + tid] = incl - cnt + wpre;
  if (tid == 0) {
    const unsigned s0 = ws[WS_CHC + b * 4 + 0];
    ws[WS_S0 + b] = s0;
    ws[WS_S01 + b] = s0 + ws[WS_CHC + b * 4 + 1];
  }
}

// Index-ordered compaction (wave-independent, no barriers in loop) -> 4B keys,
// fused pass-1 per-destblock digit histogram into H0.  (1-D XCD-grouped grid)
__global__ __launch_bounds__(TPB) void k_cscatter(const unsigned* __restrict__ gb,
                                                  const unsigned* __restrict__ ws,
                                                  unsigned* __restrict__ keyArr,
                                                  unsigned* __restrict__ H0) {
  __shared__ unsigned h2[256 * NB_S];   // 8 KB
  const int bid = blockIdx.x;
  const int b = bid & 63, blk = bid >> 6, tid = threadIdx.x;
  const int lane = tid & 63, wv = tid >> 6;
  for (int e = tid; e < 256 * NB_S; e += TPB) h2[e] = 0u;
  __syncthreads();
  const unsigned G = ws[WS_GS + b];
  unsigned base = ws[WS_COFF + b * 256 + blk * 4 + wv];
  const uint4* g4 = (const uint4*)(gb + (size_t)b * NPS + (size_t)blk * CH_C) + wv * (WCH / 4);
  unsigned* ka = keyArr + (size_t)b * KCAP;
  for (int it = 0; it < WCH / 256; ++it) {
    const uint4 v = g4[it * 64 + lane];
    unsigned k[4] = { v.x & 0x7FFFFFFFu, v.y & 0x7FFFFFFFu, v.z & 0x7FFFFFFFu, v.w & 0x7FFFFFFFu };
    bool s[4];
    unsigned cnt = 0;
#pragma unroll
    for (int c = 0; c < 4; ++c) { s[c] = (k[c] <= G); cnt += (unsigned)s[c]; }
    unsigned incl = cnt;
    for (int off = 1; off < 64; off <<= 1) {
      unsigned u = __shfl_up(incl, off, 64);
      if (lane >= off) incl += u;
    }
    const unsigned wtot = __shfl(incl, 63, 64);
    unsigned pos = base + incl - cnt;
#pragma unroll
    for (int c = 0; c < 4; ++c) {
      if (s[c]) {
        if (pos < (unsigned)KCAP) {
          ka[pos] = k[c];
          atomicAdd(&h2[(k[c] & 255u) * NB_S + pos / (unsigned)CH_S], 1u);
        }
        ++pos;
      }
    }
    base += wtot;
  }
  __syncthreads();
  unsigned* Hb = H0 + (size_t)b * 256 * NB_S;
  for (int e = tid; e < 256 * NB_S; e += TPB) {
    unsigned c = h2[e];
    if (c) atomicAdd(&Hb[e], c);
  }
}

// per-sample scan of H[b][256][NB_S] counts -> global output bases (lexicographic dig,blk)
__global__ __launch_bounds__(TPB) void k_hscan(unsigned* __restrict__ H) {
  __shared__ unsigned wsum[4];
  const int b = blockIdx.x, tid = threadIdx.x;
  const int lane = tid & 63, wv = tid >> 6;
  unsigned* Hb = H + (size_t)b * 256 * NB_S;
  unsigned row[NB_S];
  unsigned run = 0;
#pragma unroll
  for (int k = 0; k < NB_S; ++k) {
    unsigned t = Hb[tid * NB_S + k];
    row[k] = run; run += t;
  }
  unsigned incl = run;
  for (int off = 1; off < 64; off <<= 1) {
    unsigned t = __shfl_up(incl, off, 64);
    if (lane >= off) incl += t;
  }
  if (lane == 63) wsum[wv] = incl;
  __syncthreads();
  unsigned wpre = 0;
  for (int w = 0; w < wv; ++w) wpre += wsum[w];
  const unsigned excl = incl - run + wpre;
#pragma unroll
  for (int k = 0; k < NB_S; ++k) Hb[tid * NB_S + k] = row[k] + excl;
}

// One stable 8-bit LSD radix pass, TPS=1024 threads, tile=4096 records. 1-D XCD grid.
// MODE 0: input = 4B key array (comppos == position) -> records + next hist.
// MODE 1: records -> records + next hist (LDS-staged coalesced output).
// MODE 2: final (7-bit digit): rank inline -> threefry fill VALUE into fillmap[comppos].
template<int MODE>
__global__ __launch_bounds__(TPS) void k_sort8(const unsigned* __restrict__ keyIn,
                                               const uint2* __restrict__ inR,
                                               uint2* __restrict__ outR,
                                               unsigned* __restrict__ fillmap,
                                               const unsigned* __restrict__ Hcur,
                                               unsigned* __restrict__ Hnext,
                                               const unsigned* __restrict__ ws,
                                               int shift) {
  constexpr int DBITS = (MODE == 2) ? 7 : 8;
  constexpr unsigned DMASK = (1u << DBITS) - 1u;
  __shared__ unsigned wh[16][256];       // per-wave digit counts -> per-wave in-tile bases
  __shared__ unsigned gout[256];         // gbase[d] - tstart[d] (tile-local -> global)
  __shared__ unsigned gbase[256];        // running global base per digit
  __shared__ unsigned wsum[4];
  __shared__ uint2    stg[(MODE == 2) ? 1 : TILE];
  __shared__ unsigned h2[(MODE == 2) ? 1 : 256 * NB_S];
  const int bid = blockIdx.x;
  const int b = bid & 63, blk = bid >> 6, tid = threadIdx.x;
  const int lane = tid & 63, wv = tid >> 6;
  const unsigned long long ltm = (1ull << lane) - 1ull;
  const unsigned kp = min(ws[WS_KP + b], (unsigned)KCAP);
  const unsigned s0 = (unsigned)blk * CH_S;
  const unsigned s1 = min(s0 + (unsigned)CH_S, kp);
  const unsigned* ki = keyIn + (size_t)b * KCAP;
  const uint2* in = inR + (size_t)b * KCAP;
  uint2* out = outR + (size_t)b * KCAP;
  unsigned* fm = fillmap + (size_t)b * KCAP;

  // MODE 2 per-sample uniforms
  unsigned S0 = 0, S01 = 0;
  float l0 = 0, l1 = 0, l2 = 0, h0 = 0, h1 = 0, h2v = 0;
  if (MODE == 2) {
    S0 = ws[WS_S0 + b]; S01 = ws[WS_S01 + b];
    const float* mnf = (const float*)(ws + WS_MN);
    const float* mxf = (const float*)(ws + WS_MX);
    l0 = mnf[b * CCH]; l1 = mnf[b * CCH + 1]; l2 = mnf[b * CCH + 2];
    h0 = mxf[b * CCH]; h1 = mxf[b * CCH + 1]; h2v = mxf[b * CCH + 2];
  }

  for (int d = tid; d < 256; d += TPS) gbase[d] = Hcur[((size_t)b * 256 + d) * NB_S + blk];
  if (MODE != 2) for (int e = tid; e < 256 * NB_S; e += TPS) h2[e] = 0u;
  __syncthreads();

  for (unsigned t0 = s0; t0 < s1; t0 += (unsigned)TILE) {
    { uint4* w4 = (uint4*)&wh[0][0];
      w4[tid] = make_uint4(0u, 0u, 0u, 0u); }
    __syncthreads();

    // Phase A: rank within wave (order: wv, chunk, lane == memory order)
    unsigned key[4], cpp[4], wloc[4], dig[4];
    bool val[4];
    const unsigned wbase = t0 + (unsigned)wv * 256u;
#pragma unroll
    for (int c = 0; c < 4; ++c) {
      const unsigned i = wbase + (unsigned)c * 64u + (unsigned)lane;
      val[c] = (i < s1);
      if (MODE == 0) { cpp[c] = i; key[c] = val[c] ? ki[i] : 0u; }
      else { uint2 r = val[c] ? in[i] : make_uint2(0u, 0u); cpp[c] = r.x; key[c] = r.y; }
      dig[c] = (key[c] >> shift) & DMASK;
      unsigned long long peers = __ballot(val[c]);
#pragma unroll
      for (int bit = 0; bit < DBITS; ++bit) {
        unsigned long long bb = __ballot(val[c] && ((dig[c] >> bit) & 1u));
        peers &= ((dig[c] >> bit) & 1u) ? bb : ~bb;
      }
      const unsigned before = (unsigned)__popcll(peers & ltm);
      int ldr = __ffsll((unsigned long long)peers) - 1;
      if (ldr < 0) ldr = 0;
      unsigned old = 0;
      if (val[c] && lane == ldr) old = atomicAdd(&wh[wv][dig[c]], (unsigned)__popcll(peers));
      old = __shfl(old, ldr, 64);
      wloc[c] = old + before;
    }
    __syncthreads();

    // Phase B: per-digit cross-wave prefix + tile bin starts + advance gbase
    unsigned incl = 0, tot = 0;
    if (tid < 256) {
      const unsigned d = (unsigned)tid;
#pragma unroll
      for (int w = 0; w < 16; ++w) tot += wh[w][d];
      incl = tot;
      for (int off = 1; off < 64; off <<= 1) {
        unsigned t = __shfl_up(incl, off, 64);
        if (lane >= off) incl += t;
      }
      if (lane == 63) wsum[wv] = incl;
    }
    __syncthreads();
    if (tid < 256) {
      const unsigned d = (unsigned)tid;
      unsigned wpre = 0;
      for (int w = 0; w < wv; ++w) wpre += wsum[w];
      const unsigned tstart = incl - tot + wpre;
      const unsigned g = gbase[d];
      gout[d] = g - tstart;
      gbase[d] = g + tot;
      unsigned run = tstart;
#pragma unroll
      for (int w = 0; w < 16; ++w) { const unsigned t = wh[w][d]; wh[w][d] = run; run += t; }
    }
    __syncthreads();

    if (MODE != 2) {
      // Phase C: stage records into LDS in digit order
#pragma unroll
      for (int c = 0; c < 4; ++c) {
        if (val[c]) {
          uint2 r; r.x = cpp[c]; r.y = key[c];
          stg[wh[wv][dig[c]] + wloc[c]] = r;
        }
      }
      __syncthreads();
      // Phase D: coalesced write-out + fused next-pass histogram
      const unsigned nt = min((unsigned)TILE, s1 - t0);
      for (unsigned j = tid; j < nt; j += TPS) {
        const uint2 r = stg[j];
        const unsigned d = (r.y >> shift) & 255u;
        const unsigned pos = gout[d] + j;
        out[pos] = r;
        const unsigned nd = (r.y >> (shift + 8)) & 255u;
        atomicAdd(&h2[nd * NB_S + pos / (unsigned)CH_S], 1u);
      }
    } else {
      // Final pass: rank inline -> fill VALUE into fillmap[comppos]
#pragma unroll
      for (int c = 0; c < 4; ++c) {
        if (val[c]) {
          const unsigned rank = gout[dig[c]] + wh[wv][dig[c]] + wloc[c];
          unsigned res = 0xFFFFFFFFu;
          if (rank < (unsigned)KSEL) {
            const unsigned p = (unsigned)b * (unsigned)KSEL + rank;
            unsigned o0, o1;
            threefry2x32(0u, 42u, 0u, p, o0, o1);
            const unsigned bits = o0 ^ o1;
            const float u = __uint_as_float((bits >> 9) | 0x3f800000u) - 1.0f;
            const unsigned ch = (unsigned)(cpp[c] >= S0) + (unsigned)(cpp[c] >= S01);
            const float lo = (ch == 0) ? l0 : ((ch == 1) ? l1 : l2);
            const float hi = (ch == 0) ? h0 : ((ch == 1) ? h1 : h2v);
            res = __float_as_uint(lo + u * (hi - lo));
          }
          fm[cpp[c]] = res;
        }
      }
    }
    __syncthreads();   // protect wh/gout/gbase before next tile's clear
  }

  if (MODE != 2) {
    unsigned* Hb = Hnext + (size_t)b * 256 * NB_S;
    for (int e = tid; e < 256 * NB_S; e += TPS) {
      unsigned c = h2[e];
      if (c) atomicAdd(&Hb[e], c);
    }
  }
}

// Fused copy+fill: regenerates compaction positions with the SAME wave-independent
// traversal as k_cscatter; reads fill VALUES from fillmap; nt streaming for x/g/out.
__global__ __launch_bounds__(TPB) void k_fill(const u32x4* __restrict__ x4,
                                              const u32x4* __restrict__ g4all,
                                              const unsigned* __restrict__ fillmap,
                                              const unsigned* __restrict__ ws,
                                              u32x4* __restrict__ out4) {
  const int bid = blockIdx.x;
  const int b = bid & 63, blk = bid >> 6, tid = threadIdx.x;
  const int lane = tid & 63, wv = tid >> 6;
  const unsigned G = ws[WS_GS + b];
  const unsigned kp = min(ws[WS_KP + b], (unsigned)KCAP);
  unsigned base = ws[WS_COFF + b * 256 + blk * 4 + wv];
  const size_t t4 = (size_t)b * (NPS / 4) + (size_t)blk * (CH_C / 4) + (size_t)wv * (WCH / 4);
  const unsigned* fm = fillmap + (size_t)b * KCAP;
  for (int it = 0; it < WCH / 256; ++it) {
    const size_t a = t4 + it * 64 + lane;
    const u32x4 gv = __builtin_nontemporal_load(&g4all[a]);
    u32x4 xv = __builtin_nontemporal_load(&x4[a]);
    unsigned k[4] = { gv.x & 0x7FFFFFFFu, gv.y & 0x7FFFFFFFu, gv.z & 0x7FFFFFFFu, gv.w & 0x7FFFFFFFu };
    bool s[4];
    unsigned cnt = 0;
#pragma unroll
    for (int c = 0; c < 4; ++c) { s[c] = (k[c] <= G); cnt += (unsigned)s[c]; }
    unsigned incl = cnt;
    for (int off = 1; off < 64; off <<= 1) {
      unsigned u = __shfl_up(incl, off, 64);
      if (lane >= off) incl += u;
    }
    const unsigned wtot = __shfl(incl, 63, 64);
    unsigned pos = base + incl - cnt;
#pragma unroll
    for (int c = 0; c < 4; ++c) {
      if (s[c]) {
        if (pos < kp) {
          const unsigned r = fm[pos];
          if (r != 0xFFFFFFFFu) xv[c] = r;
        }
        ++pos;
      }
    }
    __builtin_nontemporal_store(xv, &out4[a]);
    base += wtot;
  }
}

extern "C" void kernel_launch(void* const* d_in, const int* in_sizes, int n_in,
                              void* d_out, int out_size, void* d_ws, size_t ws_size,
                              hipStream_t stream) {
  const float* x = (const float*)d_in[0];
  const unsigned* gb = (const unsigned*)d_in[1];   // grad bits
  float* out = (float*)d_out;
  unsigned* ws = (unsigned*)d_ws;
  if (ws_size < WS_NEEDED_BYTES) return;

  unsigned* R1 = ws + WS_FIX_END;                  // keys / records / fillmap
  unsigned* R2 = ws + WS_FIX_END + RECW;           // records
  unsigned* H0 = ws + WS_H0;
  unsigned* H1 = ws + WS_H1;
  unsigned* H2 = ws + WS_H2;
  unsigned* H3 = ws + WS_H3;

  dim3 blk(TPB);
  dim3 sblk(TPS);

  // 0. min/max partials (read-only) ; zero chCnt + hist region
  k_mnmx<<<dim3(BN * CCH * SUB), blk, 0, stream>>>((const float4*)x, ws);
  k_mnfin<<<dim3(1), blk, 0, stream>>>(ws);
  {
    const int nz = (int)(WS_FIX_END - WS_CHC);
    k_zero<<<dim3((nz + TPB - 1) / TPB), blk, 0, stream>>>(ws + WS_CHC, nz);
  }

  // 1. 22-bit prefix threshold via 11+11-bit histogram refinement
  k_thrA<<<dim3(NB_T, BN), blk, 0, stream>>>(gb, ws + WS_THA);
  k_find<<<dim3(BN), blk, 0, stream>>>(ws + WS_THA, ws, 0);
  k_thrB<<<dim3(NB_T, BN), blk, 0, stream>>>(gb, ws + WS_THB, ws);
  k_find<<<dim3(BN), blk, 0, stream>>>(ws + WS_THB, ws, 1);

  // 2. per-wave-range counts + channel totals ; scan ; compaction + pass-1 hist
  //    (1-D grids, sample = bid & 63 -> all of a sample's blocks land on one XCD)
  k_ccount<<<dim3(NB_C * BN), blk, 0, stream>>>(gb, ws);
  k_cscan<<<dim3(BN), blk, 0, stream>>>(ws);
  k_cscatter<<<dim3(NB_C * BN), blk, 0, stream>>>(gb, ws, R1, H0);

  // 3. stable LSD radix sort, 4 x 8-bit; final pass writes fill VALUES into fillmap (R1)
  k_hscan<<<dim3(BN), blk, 0, stream>>>(H0);
  k_sort8<0><<<dim3(NB_S * BN), sblk, 0, stream>>>(R1, (const uint2*)nullptr, (uint2*)R2, nullptr, H0, H1, ws, 0);
  k_hscan<<<dim3(BN), blk, 0, stream>>>(H1);
  k_sort8<1><<<dim3(NB_S * BN), sblk, 0, stream>>>(nullptr, (const uint2*)R2, (uint2*)R1, nullptr, H1, H2, ws, 8);
  k_hscan<<<dim3(BN), blk, 0, stream>>>(H2);
  k_sort8<1><<<dim3(NB_S * BN), sblk, 0, stream>>>(nullptr, (const uint2*)R1, (uint2*)R2, nullptr, H2, H3, ws, 16);
  k_hscan<<<dim3(BN), blk, 0, stream>>>(H3);
  k_sort8<2><<<dim3(NB_S * BN), sblk, 0, stream>>>(nullptr, (const uint2*)R2, (uint2*)nullptr, R1, H3, nullptr, ws, 24);

  // 4. fused copy + fill (pure streaming)
  k_fill<<<dim3(NB_C * BN), blk, 0, stream>>>((const u32x4*)x, (const u32x4*)gb, R1, ws, (u32x4*)out);
}